// Round 10
// baseline (568.248 us; speedup 1.0000x reference)
//
#include <hip/hip_runtime.h>
#include <hip/hip_bf16.h>

typedef __hip_bfloat16 bf16;
typedef __attribute__((ext_vector_type(8))) short bfrag8;
typedef __attribute__((ext_vector_type(4))) float f32x4;

#define N_LIG 4096
#define N_REC 8192
#define E_LIG 65536
#define E_REC 262144
#define F_LIGc 15
#define F_RECc 27

__device__ __forceinline__ float ldkv(const float* p, size_t i) { return p[i]; }
__device__ __forceinline__ float ldkv(const bf16* p, size_t i) { return __bfloat162float(p[i]); }
__device__ __forceinline__ short bfbits(float x) {
    bf16 b = __float2bfloat16(x);
    return *(short*)&b;
}
__device__ __forceinline__ unsigned short stg(const float* p, size_t i) {
    return (unsigned short)bfbits(p[i]);
}
__device__ __forceinline__ unsigned short stg(const bf16* p, size_t i) {
    return *(const unsigned short*)(p + i);
}
__device__ __forceinline__ void stage16(unsigned short* d, const bf16* s) {
    *(uint4*)d = *(const uint4*)s;
}
__device__ __forceinline__ void stage16(unsigned short* d, const float* s) {
    float4 a = *(const float4*)s;
    float4 b = *(const float4*)(s + 4);
    unsigned short tmp[8] = {
        (unsigned short)bfbits(a.x), (unsigned short)bfbits(a.y),
        (unsigned short)bfbits(a.z), (unsigned short)bfbits(a.w),
        (unsigned short)bfbits(b.x), (unsigned short)bfbits(b.y),
        (unsigned short)bfbits(b.z), (unsigned short)bfbits(b.w)};
    *(uint4*)d = *(uint4*)tmp;
}
__device__ __forceinline__ void cv4(bf16* d, const float* s) {
    float4 v = *(const float4*)s;
    unsigned short tmp[4] = {
        (unsigned short)bfbits(v.x), (unsigned short)bfbits(v.y),
        (unsigned short)bfbits(v.z), (unsigned short)bfbits(v.w)};
    *(uint2*)d = *(uint2*)tmp;
}

// XOR-swizzled LDS index (shorts): 64-col rows, 16B blocks permuted per-row.
__device__ __forceinline__ int swz(int row, int col) {
    return (row << 6) + ((((col >> 3) ^ row ^ (row >> 3)) & 7) << 3) + (col & 7);
}

__constant__ float c_inv_sigma[15] = {
    1.0f, 0.6666666667f, 0.4444444444f, 0.2962962963f, 0.1975308642f,
    0.1316872428f, 0.08779149520f, 0.05852766346f, 0.03901844231f,
    0.02601229487f, 0.01734152992f, 0.01156101994f, 0.007707346628f,
    0.005138231085f, 0.003425487390f};

__device__ __forceinline__ float wave_sum(float v) {
    #pragma unroll
    for (int o = 32; o > 0; o >>= 1) v += __shfl_xor(v, o, 64);
    return v;
}
__device__ __forceinline__ float quad_max(float v) {
    v = fmaxf(v, __shfl_xor(v, 1)); v = fmaxf(v, __shfl_xor(v, 2));
    v = fmaxf(v, __shfl_xor(v, 4)); v = fmaxf(v, __shfl_xor(v, 8));
    return v;
}

// ---------------- reusable prep bodies ----------------
__device__ __forceinline__ void pack_body(
    int b, int t,
    const float* w_rec1, const float* w_lig1, const float* w_rec2, const float* w_lig2,
    const float* c_rec1, const float* c_lig1,
    const float* n_rec1, const float* n_lig1, const float* n_rec2, const float* n_lig2,
    unsigned short* p_rec1, unsigned short* p_lig1,
    unsigned short* p_rec2, unsigned short* p_lig2,
    unsigned short* pc_rec1, unsigned short* pc_lig1,
    unsigned short* pn_rec1, unsigned short* pn_lig1,
    unsigned short* pn_rec2, unsigned short* pn_lig2)
{
    const float* src; unsigned short* dst; int kk, IN;
    if (b < 6)       { src = w_rec1; dst = p_rec1;  kk = b;      IN = 170; }
    else if (b < 11) { src = w_lig1; dst = p_lig1;  kk = b - 6;  IN = 158; }
    else if (b < 13) { src = w_rec2; dst = p_rec2;  kk = b - 11; IN = 64; }
    else if (b < 15) { src = w_lig2; dst = p_lig2;  kk = b - 13; IN = 64; }
    else if (b < 17) { src = c_rec1; dst = pc_rec1; kk = b - 15; IN = 64; }
    else if (b < 19) { src = c_lig1; dst = pc_lig1; kk = b - 17; IN = 64; }
    else if (b < 27) { src = n_rec1; dst = pn_rec1; kk = b - 19; IN = 256; }
    else if (b < 35) { src = n_lig1; dst = pn_lig1; kk = b - 27; IN = 256; }
    else if (b < 37) { src = n_rec2; dst = pn_rec2; kk = b - 35; IN = 64; }
    else             { src = n_lig2; dst = pn_lig2; kk = b - 37; IN = 64; }
    int wv = t >> 6, L = t & 63, lm = L & 15, qd = L >> 4;
    int n = wv * 16 + lm;
    unsigned short tmp[8];
    #pragma unroll
    for (int j = 0; j < 8; ++j) {
        int k = kk * 32 + qd * 8 + j;
        tmp[j] = (k < IN) ? (unsigned short)bfbits(src[k * 64 + n]) : (unsigned short)0;
    }
    *(uint4*)&dst[((size_t)(kk * 4 + wv) * 64 + L) * 8] = *(uint4*)tmp;
}

__device__ __forceinline__ void kv_body(
    int job, int j,
    const float* h_lig, const float* h_rec,
    const float* kwl, const float* vwl, const float* kwr, const float* vwr,
    bf16* kbl, bf16* vbl, bf16* kbr, bf16* vbr)
{
    const float *h, *w; bf16* out; int node, do_l;
    if (job < N_LIG)                  { h = h_lig; w = kwl; out = kbl; node = job;                     do_l = 1; }
    else if (job < 2 * N_LIG)         { h = h_lig; w = vwl; out = vbl; node = job - N_LIG;             do_l = 0; }
    else if (job < 2 * N_LIG + N_REC) { h = h_rec; w = kwr; out = kbr; node = job - 2 * N_LIG;         do_l = 1; }
    else                              { h = h_rec; w = vwr; out = vbr; node = job - 2 * N_LIG - N_REC; do_l = 0; }
    float xv = h[(size_t)node * 64 + j];
    float acc = 0.f;
    #pragma unroll
    for (int i = 0; i < 64; ++i) acc += __shfl(xv, i, 64) * w[i * 64 + j];
    if (do_l) acc = acc > 0.f ? acc : 0.01f * acc;
    out[(size_t)node * 64 + j] = __float2bfloat16(acc);
}

__device__ __forceinline__ void mask_body(
    unsigned char* tr, unsigned char* tc, int bx, int by, int t,
    const float* mask, unsigned long long* mq, unsigned long long* mqT, int R, int C)
{
    int r0 = by * 64, c0 = bx * 64;
    int cs = (t & 15) * 4;
    #pragma unroll
    for (int rr = 0; rr < 4; ++rr) {
        int r = (t >> 4) + rr * 16;
        const float* mp = &mask[(size_t)(r0 + r) * C + c0 + cs];
        unsigned char b0 = mp[0] != 0.f, b1 = mp[1] != 0.f;
        unsigned char b2 = mp[2] != 0.f, b3 = mp[3] != 0.f;
        tr[r * 68 + cs + 0] = b0; tr[r * 68 + cs + 1] = b1;
        tr[r * 68 + cs + 2] = b2; tr[r * 68 + cs + 3] = b3;
        tc[(cs + 0) * 68 + r] = b0; tc[(cs + 1) * 68 + r] = b1;
        tc[(cs + 2) * 68 + r] = b2; tc[(cs + 3) * 68 + r] = b3;
    }
    __syncthreads();
    if (t < 128) {
        const unsigned* p = (t < 64) ? (const unsigned*)&tr[t * 68]
                                     : (const unsigned*)&tc[(t - 64) * 68];
        unsigned lo = 0, hi = 0;
        #pragma unroll
        for (int i = 0; i < 8; ++i)
            lo |= (((p[i] & 0x01010101u) * 0x01020408u) >> 24 & 0xFu) << (4 * i);
        #pragma unroll
        for (int i = 8; i < 16; ++i)
            hi |= (((p[i] & 0x01010101u) * 0x01020408u) >> 24 & 0xFu) << (4 * (i - 8));
        unsigned long long w = (unsigned long long)lo | ((unsigned long long)hi << 32);
        if (t < 64) mq[(size_t)(c0 >> 6) * R + r0 + t] = w;
        else        mqT[(size_t)(r0 >> 6) * C + c0 + (t - 64)] = w;
    }
}

// ============ fused prep kernel (tier 0): mask + cvt(x4) + kv + zeroA + hist + pack ============
#define NB_MASK   ((N_REC / 64) * (N_LIG / 64))                                   // 8192
#define N_CVT     (N_LIG * 64 + N_REC * 64 + E_LIG * F_LIGc + E_REC * F_RECc)     // 8847360
#define NB_CVT4   (N_CVT / 1024)                                                   // 8640
#define NB_KV     (2 * (N_LIG + N_REC) / 4)                                        // 6144
#define N_ZEROA   (N_LIG * 64 + N_REC * 64 + N_LIG * 3 + N_REC * 3)                // 823296
#define NB_ZEROA  (N_ZEROA / 256)                                                  // 3216
#define N_ZERO    (N_ZEROA + N_LIG + N_REC)                                        // full (tier1/2)
#define NB_HIST   ((E_LIG + E_REC) / 256)                                          // 1280
#define NB_PACK   39
#define NB_PREP   (NB_MASK + NB_CVT4 + NB_KV + NB_ZEROA + NB_HIST + NB_PACK)

__global__ __launch_bounds__(256) void prep_kernel(
    const float* __restrict__ mask, unsigned long long* __restrict__ mq,
    unsigned long long* __restrict__ mqT,
    const float* __restrict__ h_lig, bf16* __restrict__ hb_l,
    const float* __restrict__ h_rec, bf16* __restrict__ hb_r,
    const float* __restrict__ ef_l, bf16* __restrict__ efb_l,
    const float* __restrict__ ef_r, bf16* __restrict__ efb_r,
    const float* __restrict__ kwl, const float* __restrict__ vwl,
    const float* __restrict__ kwr, const float* __restrict__ vwr,
    bf16* __restrict__ kbl, bf16* __restrict__ vbl,
    bf16* __restrict__ kbr, bf16* __restrict__ vbr,
    float* __restrict__ zp,
    const int* __restrict__ dl, const int* __restrict__ dr,
    int* __restrict__ cl, int* __restrict__ cr,
    const float* w_rec1, const float* w_lig1, const float* w_rec2, const float* w_lig2,
    const float* c_rec1, const float* c_lig1,
    const float* n_rec1, const float* n_lig1, const float* n_rec2, const float* n_lig2,
    unsigned short* p_rec1, unsigned short* p_lig1,
    unsigned short* p_rec2, unsigned short* p_lig2,
    unsigned short* pc_rec1, unsigned short* pc_lig1,
    unsigned short* pn_rec1, unsigned short* pn_lig1,
    unsigned short* pn_rec2, unsigned short* pn_lig2)
{
    __shared__ unsigned char tr[64 * 68];
    __shared__ unsigned char tc[64 * 68];
    int b = blockIdx.x, t = threadIdx.x;
    if (b < NB_MASK) {
        mask_body(tr, tc, b & 127, b >> 7, t, mask, mq, mqT, N_LIG, N_REC);
        return;
    }
    b -= NB_MASK;
    if (b < NB_CVT4) {
        int i = (b * 256 + t) * 4;
        if (i < N_LIG * 64) { cv4(hb_l + i, h_lig + i); return; }
        i -= N_LIG * 64;
        if (i < N_REC * 64) { cv4(hb_r + i, h_rec + i); return; }
        i -= N_REC * 64;
        if (i < E_LIG * F_LIGc) { cv4(efb_l + i, ef_l + i); return; }
        i -= E_LIG * F_LIGc;
        cv4(efb_r + i, ef_r + i);
        return;
    }
    b -= NB_CVT4;
    if (b < NB_KV) {
        kv_body(b * 4 + (t >> 6), t & 63, h_lig, h_rec, kwl, vwl, kwr, vwr,
                kbl, vbl, kbr, vbr);
        return;
    }
    b -= NB_KV;
    if (b < NB_ZEROA) {
        zp[b * 256 + t] = 0.f;
        return;
    }
    b -= NB_ZEROA;
    if (b < NB_HIST) {
        int i = b * 256 + t;
        if (i < E_LIG) atomicAdd(&cl[dl[i]], 1);
        else atomicAdd(&cr[dr[i - E_LIG]], 1);
        return;
    }
    b -= NB_HIST;
    pack_body(b, t, w_rec1, w_lig1, w_rec2, w_lig2, c_rec1, c_lig1,
              n_rec1, n_lig1, n_rec2, n_lig2,
              p_rec1, p_lig1, p_rec2, p_lig2, pc_rec1, pc_lig1,
              pn_rec1, pn_lig1, pn_rec2, pn_lig2);
}

// ---------------- standalone prep kernels ----------------
__global__ void zero_kernel(float* __restrict__ p, int n) {
    int i = blockIdx.x * blockDim.x + threadIdx.x;
    if (i < n) p[i] = 0.f;
}
__global__ void hist2_kernel(const int* __restrict__ dl, const int* __restrict__ dr,
                             int* __restrict__ cl, int* __restrict__ cr) {
    int i = blockIdx.x * 256 + threadIdx.x;
    if (i < E_LIG) { atomicAdd(&cl[dl[i]], 1); return; }
    i -= E_LIG;
    if (i < E_REC) atomicAdd(&cr[dr[i]], 1);
}
__global__ __launch_bounds__(256) void pack_frags(
    const float* w_rec1, const float* w_lig1, const float* w_rec2, const float* w_lig2,
    const float* c_rec1, const float* c_lig1,
    const float* n_rec1, const float* n_lig1, const float* n_rec2, const float* n_lig2,
    unsigned short* p_rec1, unsigned short* p_lig1,
    unsigned short* p_rec2, unsigned short* p_lig2,
    unsigned short* pc_rec1, unsigned short* pc_lig1,
    unsigned short* pn_rec1, unsigned short* pn_lig1,
    unsigned short* pn_rec2, unsigned short* pn_lig2)
{
    pack_body(blockIdx.x, threadIdx.x, w_rec1, w_lig1, w_rec2, w_lig2, c_rec1, c_lig1,
              n_rec1, n_lig1, n_rec2, n_lig2,
              p_rec1, p_lig1, p_rec2, p_lig2, pc_rec1, pc_lig1,
              pn_rec1, pn_lig1, pn_rec2, pn_lig2);
}
__global__ __launch_bounds__(256) void kv_proj_kernel(
    const float* __restrict__ h_lig, const float* __restrict__ h_rec,
    const float* __restrict__ kwl, const float* __restrict__ vwl,
    const float* __restrict__ kwr, const float* __restrict__ vwr,
    bf16* __restrict__ kbl, bf16* __restrict__ vbl,
    bf16* __restrict__ kbr, bf16* __restrict__ vbr)
{
    kv_body(blockIdx.x * 4 + (threadIdx.x >> 6), threadIdx.x & 63,
            h_lig, h_rec, kwl, vwl, kwr, vwr, kbl, vbl, kbr, vbr);
}

__global__ __launch_bounds__(256) void scan2_kernel(
    const int* __restrict__ cl, int* __restrict__ curl,
    const int* __restrict__ cr, int* __restrict__ curr)
{
    const int* counts = blockIdx.x ? cr : cl;
    int* cursor = blockIdx.x ? curr : curl;
    int n = blockIdx.x ? N_REC : N_LIG;
    __shared__ int part[256];
    int t = threadIdx.x;
    int c = n / 256;
    int base = t * c;
    int s = 0;
    for (int i = 0; i < c; ++i) s += counts[base + i];
    part[t] = s;
    __syncthreads();
    for (int o = 1; o < 256; o <<= 1) {
        int u = (t >= o) ? part[t - o] : 0;
        __syncthreads();
        part[t] += u;
        __syncthreads();
    }
    int run = part[t] - s;
    for (int i = 0; i < c; ++i) {
        cursor[base + i] = run;
        run += counts[base + i];
    }
}

__global__ void scatter2_kernel(const int* __restrict__ dl, const int* __restrict__ dr,
                                int* __restrict__ curl, int* __restrict__ curr,
                                int* __restrict__ ordl, int* __restrict__ ordr) {
    int i = blockIdx.x * 256 + threadIdx.x;
    if (i < E_LIG) { ordl[atomicAdd(&curl[dl[i]], 1)] = i; return; }
    i -= E_LIG;
    if (i < E_REC) ordr[atomicAdd(&curr[dr[i]], 1)] = i;
}

// ============ edge body (shared-buffer carve-out) ============
template <int F, int K1S, typename HT>
__device__ __forceinline__ void edge_body(
    char* sbuf, int ebid,
    const int* __restrict__ order,
    const float* __restrict__ coords, const HT* __restrict__ h,
    const int* __restrict__ src, const int* __restrict__ dst,
    const HT* __restrict__ efeat,
    const unsigned short* __restrict__ w1p, const float* __restrict__ b1,
    const float* __restrict__ g, const float* __restrict__ bt,
    const unsigned short* __restrict__ w2p, const float* __restrict__ b2,
    const unsigned short* __restrict__ c1p, const float* __restrict__ cb1,
    const float* __restrict__ cw2, const float* __restrict__ cb2,
    float* __restrict__ aggr, float* __restrict__ xacc)
{
    constexpr int IN = 143 + F;
    constexpr int KP = K1S * 32 + 8;
    constexpr int XB = 64 * KP * 2;
    static_assert(XB >= 64 * 68 * 4, "msgf f32 alias must fit in xb");
    static_assert(XB >= 64 * 72 * 2, "h1b alias must fit in xb");
    unsigned short* xb   = (unsigned short*)sbuf;
    unsigned short* h1b  = (unsigned short*)sbuf;
    float*          msgf = (float*)sbuf;
    float* wsum1   = (float*)(sbuf + XB);
    float* wsum2   = (float*)(sbuf + XB + 1024);
    float* stat_m  = (float*)(sbuf + XB + 2048);
    float* stat_r  = (float*)(sbuf + XB + 2304);
    float* coefp   = (float*)(sbuf + XB + 2560);
    float* coef_all= (float*)(sbuf + XB + 3584);
    int*   srcs    = (int*)(sbuf + XB + 3840);
    int*   dsts    = (int*)(sbuf + XB + 4096);
    int*   ords    = (int*)(sbuf + XB + 4352);
    float* xr_s    = (float*)(sbuf + XB + 4608);
    float* d2s     = (float*)(sbuf + XB + 5376);

    const int t  = threadIdx.x;
    const int wv = t >> 6;
    const int L  = t & 63;
    const int lm = L & 15;
    const int qd = L >> 4;
    const int e0 = ebid * 64;
    const int n  = wv * 16 + lm;

    bfrag8 w1f[K1S], w2f[2];
    #pragma unroll
    for (int kk = 0; kk < K1S; ++kk)
        w1f[kk] = *(const bfrag8*)&w1p[((size_t)(kk * 4 + wv) * 64 + L) * 8];
    #pragma unroll
    for (int kk = 0; kk < 2; ++kk)
        w2f[kk] = *(const bfrag8*)&w2p[((size_t)(kk * 4 + wv) * 64 + L) * 8];
    const float b1n = b1[n], b2n = b2[n], cb1n = cb1[n], cw2n = cw2[n];
    const float gn = g[n], btn = bt[n];

    if (t < 64) {
        int e = order[e0 + t];
        int s = src[e], d = dst[e];
        ords[t] = e; srcs[t] = s; dsts[t] = d;
        float x0 = coords[s * 3 + 0] - coords[d * 3 + 0];
        float x1 = coords[s * 3 + 1] - coords[d * 3 + 1];
        float x2 = coords[s * 3 + 2] - coords[d * 3 + 2];
        xr_s[t * 3 + 0] = x0; xr_s[t * 3 + 1] = x1; xr_s[t * 3 + 2] = x2;
        d2s[t] = x0 * x0 + x1 * x1 + x2 * x2;
    }
    __syncthreads();

    #pragma unroll
    for (int u = 0; u < 4; ++u) {
        int idx = t + 256 * u;
        int e = idx >> 4, c = idx & 15;
        int node = (c < 8) ? srcs[e] : dsts[e];
        stage16(&xb[e * KP + c * 8], h + (size_t)node * 64 + (c & 7) * 8);
    }
    for (int idx = t; idx < 64 * F; idx += 256) {
        int e = idx / F, f = idx - e * F;
        xb[e * KP + 128 + f] = stg(efeat, (size_t)ords[e] * F + f);
    }
    for (int idx = t; idx < 64 * 15; idx += 256) {
        int e = idx / 15, s5 = idx - e * 15;
        xb[e * KP + 128 + F + s5] = bfbits(__expf(-d2s[e] * c_inv_sigma[s5]));
    }
    {
        constexpr int PER = K1S * 32 - IN;
        for (int idx = t; idx < 64 * PER; idx += 256) {
            int e = idx / PER, k = idx - e * PER;
            xb[e * KP + IN + k] = 0;
        }
    }
    __syncthreads();

    // ---- GEMM 1 + bias/lrelu + LN partial sums via shfl ----
    float vreg[4][4];
    #pragma unroll
    for (int m = 0; m < 4; ++m) {
        f32x4 acc = {0.f, 0.f, 0.f, 0.f};
        #pragma unroll
        for (int kk = 0; kk < K1S; ++kk) {
            bfrag8 a = *(const bfrag8*)&xb[(m * 16 + lm) * KP + kk * 32 + qd * 8];
            acc = __builtin_amdgcn_mfma_f32_16x16x32_bf16(a, w1f[kk], acc, 0, 0, 0);
        }
        #pragma unroll
        for (int r = 0; r < 4; ++r) {
            float v = acc[r] + b1n;
            v = v > 0.f ? v : 0.01f * v;
            vreg[m][r] = v;
            float a1 = v, a2 = v * v;
            a1 += __shfl_xor(a1, 1); a2 += __shfl_xor(a2, 1);
            a1 += __shfl_xor(a1, 2); a2 += __shfl_xor(a2, 2);
            a1 += __shfl_xor(a1, 4); a2 += __shfl_xor(a2, 4);
            a1 += __shfl_xor(a1, 8); a2 += __shfl_xor(a2, 8);
            if (lm == 0) {
                wsum1[wv * 64 + m * 16 + qd * 4 + r] = a1;
                wsum2[wv * 64 + m * 16 + qd * 4 + r] = a2;
            }
        }
    }
    __syncthreads();
    if (t < 64) {
        float s1 = wsum1[t] + wsum1[64 + t] + wsum1[128 + t] + wsum1[192 + t];
        float s2 = wsum2[t] + wsum2[64 + t] + wsum2[128 + t] + wsum2[192 + t];
        float mean = s1 * (1.f / 64.f);
        float var = s2 * (1.f / 64.f) - mean * mean;
        stat_m[t] = mean;
        stat_r[t] = rsqrtf(fmaxf(var, 0.f) + 1e-5f);
    }
    __syncthreads();

    #pragma unroll
    for (int m = 0; m < 4; ++m)
        #pragma unroll
        for (int r = 0; r < 4; ++r) {
            int row = m * 16 + qd * 4 + r;
            float v = (vreg[m][r] - stat_m[row]) * stat_r[row] * gn + btn;
            h1b[row * 72 + n] = bfbits(v);
        }
    __syncthreads();

    // ---- GEMM 2 ----
    f32x4 acc2[4];
    #pragma unroll
    for (int m = 0; m < 4; ++m) {
        f32x4 acc = {0.f, 0.f, 0.f, 0.f};
        #pragma unroll
        for (int kk = 0; kk < 2; ++kk) {
            bfrag8 a = *(const bfrag8*)&h1b[(m * 16 + lm) * 72 + kk * 32 + qd * 8];
            acc = __builtin_amdgcn_mfma_f32_16x16x32_bf16(a, w2f[kk], acc, 0, 0, 0);
        }
        acc2[m] = acc;
    }
    __syncthreads();
    #pragma unroll
    for (int m = 0; m < 4; ++m)
        #pragma unroll
        for (int r = 0; r < 4; ++r)
            msgf[(m * 16 + qd * 4 + r) * 68 + n] = acc2[m][r] + b2n;
    __syncthreads();

    // ---- run-aggregated aggr atomics ----
    {
        int j = t & 63, q = t >> 6;
        float acc = 0.f;
        #pragma unroll
        for (int e = q * 16; e < q * 16 + 16; ++e) {
            acc += msgf[e * 68 + j];
            bool flush = (e - q * 16 == 15) || (dsts[e + 1] != dsts[e]);
            if (flush) {
                atomicAdd(&aggr[(size_t)dsts[e] * 64 + j], acc);
                acc = 0.f;
            }
        }
    }

    // ---- GEMM 3 ----
    bfrag8 c1f[2];
    #pragma unroll
    for (int kk = 0; kk < 2; ++kk)
        c1f[kk] = *(const bfrag8*)&c1p[((size_t)(kk * 4 + wv) * 64 + L) * 8];
    #pragma unroll
    for (int m = 0; m < 4; ++m) {
        f32x4 acc = {0.f, 0.f, 0.f, 0.f};
        #pragma unroll
        for (int kk = 0; kk < 2; ++kk) {
            const float* mp = &msgf[(m * 16 + lm) * 68 + kk * 32 + qd * 8];
            f32x4 p0 = *(const f32x4*)mp;
            f32x4 p1 = *(const f32x4*)(mp + 4);
            unsigned short tb[8];
            #pragma unroll
            for (int j = 0; j < 4; ++j) {
                tb[j]     = (unsigned short)bfbits(p0[j]);
                tb[4 + j] = (unsigned short)bfbits(p1[j]);
            }
            bfrag8 a = *(bfrag8*)tb;
            acc = __builtin_amdgcn_mfma_f32_16x16x32_bf16(a, c1f[kk], acc, 0, 0, 0);
        }
        #pragma unroll
        for (int r = 0; r < 4; ++r) {
            float v = acc[r] + cb1n;
            v = v > 0.f ? v : 0.01f * v;
            v *= cw2n;
            v += __shfl_xor(v, 1);
            v += __shfl_xor(v, 2);
            v += __shfl_xor(v, 4);
            v += __shfl_xor(v, 8);
            if (lm == 0) coefp[wv * 64 + m * 16 + qd * 4 + r] = v;
        }
    }
    __syncthreads();
    if (t < 64)
        coef_all[t] = coefp[t] + coefp[64 + t] + coefp[128 + t] + coefp[192 + t] + cb2[0];
    __syncthreads();

    if (t < 12) {
        int q = t / 3, ax = t - q * 3;
        float acc = 0.f;
        for (int e = q * 16; e < q * 16 + 16; ++e) {
            acc += xr_s[e * 3 + ax] * coef_all[e];
            bool flush = (e - q * 16 == 15) || (dsts[e + 1] != dsts[e]);
            if (flush) {
                atomicAdd(&xacc[dsts[e] * 3 + ax], acc);
                acc = 0.f;
            }
        }
    }
}

// ============ attention body: Q-frags in registers, 3-buffer LDS (25088 B) ============
template <int MMODE>
__device__ __forceinline__ void attn_body(
    char* sbuf, int bid, int nb1,
    const float* __restrict__ h1, const float* __restrict__ qw1,
    const bf16* __restrict__ k1, const bf16* __restrict__ v1,
    const unsigned long long* __restrict__ mq1, const float* __restrict__ mf1, long mrs1, long mcs1,
    float* __restrict__ pO1, float* __restrict__ pM1, float* __restrict__ pL1,
    int nrows1, int ncols1, int nsplit1,
    const float* __restrict__ h2, const float* __restrict__ qw2,
    const bf16* __restrict__ k2, const bf16* __restrict__ v2,
    const unsigned long long* __restrict__ mq2, const float* __restrict__ mf2, long mrs2, long mcs2,
    float* __restrict__ pO2, float* __restrict__ pM2, float* __restrict__ pL2,
    int nrows2, int ncols2, int nsplit2)
{
    const float *h, *qw, *mf;
    const bf16 *kkp, *vvp;
    const unsigned long long* mq;
    long mrs, mcs;
    float *pO, *pM, *pL;
    int n_rows, n_cols, nsplit;
    if (bid < nb1) {
        h = h1; qw = qw1; kkp = k1; vvp = v1; mq = mq1; mf = mf1; mrs = mrs1; mcs = mcs1;
        pO = pO1; pM = pM1; pL = pL1; n_rows = nrows1; n_cols = ncols1; nsplit = nsplit1;
    } else {
        h = h2; qw = qw2; kkp = k2; vvp = v2; mq = mq2; mf = mf2; mrs = mrs2; mcs = mcs2;
        pO = pO2; pM = pM2; pL = pL2; n_rows = nrows2; n_cols = ncols2; nsplit = nsplit2;
        bid -= nb1;
    }

    unsigned short* sP = (unsigned short*)sbuf;
    unsigned short* sK = (unsigned short*)(sbuf + 8192);
    unsigned short* sV = (unsigned short*)(sbuf + 16384);
    uint2* mtq = (uint2*)(sbuf + 24576);
    unsigned char* mt = (unsigned char*)(sbuf + 24576);

    const int t  = threadIdx.x;
    const int wv = t >> 6;
    const int lm = t & 15;
    const int qd = (t & 63) >> 4;
    const int rb = bid / nsplit;
    const int sp = bid - rb * nsplit;
    const int r0 = rb * 64;
    const int cols_per = n_cols / nsplit;
    const int c_begin = sp * cols_per;

    const int cP = t >> 3, segP = (t & 7) * 8;

    // ---- prologue staging: h -> sP (rows), qw^T -> sK ----
    #pragma unroll
    for (int u = 0; u < 2; ++u) {
        int rr = cP + 32 * u;
        const float* hp = h + (size_t)(r0 + rr) * 64 + segP;
        unsigned short tmp[8];
        #pragma unroll
        for (int j = 0; j < 8; ++j) tmp[j] = bfbits(hp[j]);
        *(uint4*)&sP[swz(rr, segP)] = *(uint4*)tmp;
        const float* qp = qw + (size_t)rr * 64 + segP;
        #pragma unroll
        for (int j = 0; j < 8; ++j) sK[swz(segP + j, rr)] = bfbits(qp[j]);
    }

    // ---- prefetch tile 0 ----
    uint4 kreg[2], vreg[2];
    unsigned long long mregq = 0;
    kreg[0] = *(const uint4*)(kkp + (size_t)(c_begin + cP) * 64 + segP);
    kreg[1] = *(const uint4*)(kkp + (size_t)(c_begin + cP + 32) * 64 + segP);
    vreg[0] = *(const uint4*)(vvp + (size_t)(c_begin + cP) * 64 + segP);
    vreg[1] = *(const uint4*)(vvp + (size_t)(c_begin + cP + 32) * 64 + segP);
    if (MMODE == 0 && t < 64)
        mregq = mq[(size_t)(c_begin >> 6) * n_rows + r0 + t];
    __syncthreads();

    // ---- prologue: q = lrelu(h @ qw) into regs ----
    float qv[4][4];
    {
        bfrag8 a0 = *(const bfrag8*)&sP[swz(wv * 16 + lm, qd * 8)];
        bfrag8 a1 = *(const bfrag8*)&sP[swz(wv * 16 + lm, 32 + qd * 8)];
        #pragma unroll
        for (int ns = 0; ns < 4; ++ns) {
            f32x4 acc = {0.f, 0.f, 0.f, 0.f};
            bfrag8 b0 = *(const bfrag8*)&sK[swz(ns * 16 + lm, qd * 8)];
            bfrag8 b1 = *(const bfrag8*)&sK[swz(ns * 16 + lm, 32 + qd * 8)];
            acc = __builtin_amdgcn_mfma_f32_16x16x32_bf16(a0, b0, acc, 0, 0, 0);
            acc = __builtin_amdgcn_mfma_f32_16x16x32_bf16(a1, b1, acc, 0, 0, 0);
            #pragma unroll
            for (int r = 0; r < 4; ++r) {
                float v = acc[r];
                qv[ns][r] = v > 0.f ? v : 0.01f * v;
            }
        }
    }
    __syncthreads();

    // ---- transpose q through sP, pick up loop-invariant A-fragments ----
    #pragma unroll
    for (int ns = 0; ns < 4; ++ns)
        #pragma unroll
        for (int r = 0; r < 4; ++r)
            sP[swz(wv * 16 + qd * 4 + r, ns * 16 + lm)] = bfbits(qv[ns][r]);
    __syncthreads();
    bfrag8 aq0 = *(const bfrag8*)&sP[swz(wv * 16 + lm, qd * 8)];
    bfrag8 aq1 = *(const bfrag8*)&sP[swz(wv * 16 + lm, 32 + qd * 8)];

    float rm[4];
    #pragma unroll
    for (int r = 0; r < 4; ++r) rm[r] = -1e30f;
    f32x4 o[4];
    #pragma unroll
    for (int ds = 0; ds < 4; ++ds) o[ds] = (f32x4){0.f, 0.f, 0.f, 0.f};
    f32x4 osum = {0.f, 0.f, 0.f, 0.f};
    const short ONE = (short)0x3F80;
    const bfrag8 bones = {ONE, ONE, ONE, ONE, ONE, ONE, ONE, ONE};

    const int nt = cols_per / 64;
    for (int tile = 0; tile < nt; ++tile) {
        #pragma unroll
        for (int u = 0; u < 2; ++u) {
            int cc = cP + 32 * u;
            *(uint4*)&sK[swz(cc, segP)] = kreg[u];
            unsigned x0 = vreg[u].x, x1 = vreg[u].y, x2 = vreg[u].z, x3 = vreg[u].w;
            sV[swz(segP + 0, cc)] = (unsigned short)x0;
            sV[swz(segP + 1, cc)] = (unsigned short)(x0 >> 16);
            sV[swz(segP + 2, cc)] = (unsigned short)x1;
            sV[swz(segP + 3, cc)] = (unsigned short)(x1 >> 16);
            sV[swz(segP + 4, cc)] = (unsigned short)x2;
            sV[swz(segP + 5, cc)] = (unsigned short)(x2 >> 16);
            sV[swz(segP + 6, cc)] = (unsigned short)x3;
            sV[swz(segP + 7, cc)] = (unsigned short)(x3 >> 16);
        }
        if (MMODE == 0) {
            if (t < 64) mtq[t] = make_uint2((unsigned)mregq, (unsigned)(mregq >> 32));
        } else {
            int c0 = c_begin + tile * 64;
            #pragma unroll
            for (int u = 0; u < 16; ++u) {
                int i = t + 256 * u;
                int r = i >> 6, c = i & 63;
                mt[r * 80 + c] = (unsigned char)(
                    mf[(size_t)(r0 + r) * mrs + (size_t)(c0 + c) * mcs] != 0.f);
            }
        }
        __syncthreads();

        if (tile + 1 < nt) {
            int c0n = c_begin + (tile + 1) * 64;
            kreg[0] = *(const uint4*)(kkp + (size_t)(c0n + cP) * 64 + segP);
            kreg[1] = *(const uint4*)(kkp + (size_t)(c0n + cP + 32) * 64 + segP);
            vreg[0] = *(const uint4*)(vvp + (size_t)(c0n + cP) * 64 + segP);
            vreg[1] = *(const uint4*)(vvp + (size_t)(c0n + cP + 32) * 64 + segP);
            if (MMODE == 0 && t < 64)
                mregq = mq[(size_t)(c0n >> 6) * n_rows + r0 + t];
        }

        f32x4 s[4];
        #pragma unroll
        for (int ns = 0; ns < 4; ++ns) {
            f32x4 acc = {0.f, 0.f, 0.f, 0.f};
            bfrag8 b0 = *(const bfrag8*)&sK[swz(ns * 16 + lm, qd * 8)];
            bfrag8 b1 = *(const bfrag8*)&sK[swz(ns * 16 + lm, 32 + qd * 8)];
            acc = __builtin_amdgcn_mfma_f32_16x16x32_bf16(aq0, b0, acc, 0, 0, 0);
            acc = __builtin_amdgcn_mfma_f32_16x16x32_bf16(aq1, b1, acc, 0, 0, 0);
            s[ns] = acc;
        }

        float alpha[4];
        #pragma unroll
        for (int r = 0; r < 4; ++r) {
            int rloc = wv * 16 + qd * 4 + r;
            float v0, v1, v2, v3;
            if (MMODE == 0) {
                uint2 w = mtq[rloc];
                v0 = (w.x >> lm) & 1        ? s[0][r] : -1000.f;
                v1 = (w.x >> (16 + lm)) & 1 ? s[1][r] : -1000.f;
                v2 = (w.y >> lm) & 1        ? s[2][r] : -1000.f;
                v3 = (w.y >> (16 + lm)) & 1 ? s[3][r] : -1000.f;
            } else {
                v0 = mt[rloc * 80 +  0 + lm] ? s[0][r] : -1000.f;
                v1 = mt[rloc * 80 + 16 + lm] ? s[1][r] : -1000.f;
                v2 = mt[rloc * 80 + 32 + lm] ? s[2][r] : -1000.f;
                v3 = mt[rloc * 80 + 48 + lm] ? s[3][r] : -1000.f;
            }
            float mx = quad_max(fmaxf(fmaxf(v0, v1), fmaxf(v2, v3)));
            float mn = fmaxf(rm[r], mx);
            float al = __expf(rm[r] - mn);
            rm[r] = mn; alpha[r] = al;
            float p0 = __expf(v0 - mn), p1 = __expf(v1 - mn);
            float p2 = __expf(v2 - mn), p3 = __expf(v3 - mn);
            sP[swz(rloc,  0 + lm)] = bfbits(p0);
            sP[swz(rloc, 16 + lm)] = bfbits(p1);
            sP[swz(rloc, 32 + lm)] = bfbits(p2);
            sP[swz(rloc, 48 + lm)] = bfbits(p3);
            osum[r] *= al;
        }
        #pragma unroll
        for (int ds = 0; ds < 4; ++ds)
            #pragma unroll
            for (int r = 0; r < 4; ++r) o[ds][r] *= alpha[r];

        __builtin_amdgcn_wave_barrier();
        asm volatile("" ::: "memory");

        {
            bfrag8 a0 = *(const bfrag8*)&sP[swz(wv * 16 + lm, qd * 8)];
            bfrag8 a1 = *(const bfrag8*)&sP[swz(wv * 16 + lm, 32 + qd * 8)];
            #pragma unroll
            for (int ds = 0; ds < 4; ++ds) {
                bfrag8 b0 = *(const bfrag8*)&sV[swz(ds * 16 + lm, qd * 8)];
                bfrag8 b1 = *(const bfrag8*)&sV[swz(ds * 16 + lm, 32 + qd * 8)];
                o[ds] = __builtin_amdgcn_mfma_f32_16x16x32_bf16(a0, b0, o[ds], 0, 0, 0);
                o[ds] = __builtin_amdgcn_mfma_f32_16x16x32_bf16(a1, b1, o[ds], 0, 0, 0);
            }
            osum = __builtin_amdgcn_mfma_f32_16x16x32_bf16(a0, bones, osum, 0, 0, 0);
            osum = __builtin_amdgcn_mfma_f32_16x16x32_bf16(a1, bones, osum, 0, 0, 0);
        }
        __syncthreads();
    }

    #pragma unroll
    for (int ds = 0; ds < 4; ++ds)
        #pragma unroll
        for (int r = 0; r < 4; ++r) {
            int row = r0 + wv * 16 + qd * 4 + r;
            pO[((size_t)sp * n_rows + row) * 64 + ds * 16 + lm] = o[ds][r];
        }
    if (lm == 0) {
        #pragma unroll
        for (int r = 0; r < 4; ++r) {
            int row = r0 + wv * 16 + qd * 4 + r;
            pM[(size_t)sp * n_rows + row] = rm[r];
            pL[(size_t)sp * n_rows + row] = osum[r];
        }
    }
}

// ============ mega kernel: LJF ordering — ALL attn blocks first, then edges ============
__global__ __launch_bounds__(256, 4) void mega_kernel(
    int nb1,
    const float* h1, const float* qw1, const bf16* k1, const bf16* v1,
    const unsigned long long* mq1, float* pO1, float* pM1, float* pL1,
    int nrows1, int ncols1, int ns1,
    const float* h2, const float* qw2, const bf16* k2, const bf16* v2,
    const unsigned long long* mq2, float* pO2, float* pM2, float* pL2,
    int nrows2, int ncols2, int ns2,
    const int* ordR, const float* coordsR, const bf16* hR,
    const int* srcR, const int* dstR, const bf16* efR,
    const unsigned short* w1pR, const float* b1R, const float* gR, const float* btR,
    const unsigned short* w2pR, const float* b2R,
    const unsigned short* c1pR, const float* cb1R, const float* cw2R, const float* cb2R,
    float* aggrR, float* xaccR,
    const int* ordL, const float* coordsL, const bf16* hL,
    const int* srcL, const int* dstL, const bf16* efL,
    const unsigned short* w1pL, const float* b1L, const float* gL, const float* btL,
    const unsigned short* w2pL, const float* b2L,
    const unsigned short* c1pL, const float* cb1L, const float* cw2L, const float* cb2L,
    float* aggrL, float* xaccL)
{
    __shared__ __align__(16) char sbuf[31232];
    int bid = blockIdx.x;
    const int nbAtt = (N_LIG / 64) * ns1 + (N_REC / 64) * ns2;
    if (bid < nbAtt) {
        attn_body<0>(sbuf, bid, nb1,
            h1, qw1, k1, v1, mq1, (const float*)0, 0L, 0L, pO1, pM1, pL1, nrows1, ncols1, ns1,
            h2, qw2, k2, v2, mq2, (const float*)0, 0L, 0L, pO2, pM2, pL2, nrows2, ncols2, ns2);
    } else {
        int eid = bid - nbAtt;
        if (eid < E_REC / 64)
            edge_body<F_RECc, 6, bf16>(sbuf, eid, ordR, coordsR, hR, srcR, dstR, efR,
                w1pR, b1R, gR, btR, w2pR, b2R, c1pR, cb1R, cw2R, cb2R, aggrR, xaccR);
        else
            edge_body<F_LIGc, 5, bf16>(sbuf, eid - E_REC / 64, ordL, coordsL, hL, srcL, dstL, efL,
                w1pL, b1L, gL, btL, w2pL, b2L, c1pL, cb1L, cw2L, cb2L, aggrL, xaccL);
    }
}

// ---- standalone fallbacks (tier 1/2) ----
template <int F, int K1S>
__global__ __launch_bounds__(256, 4) void edge_mfma_f(
    const int* order, const float* coords, const float* h,
    const int* src, const int* dst, const float* efeat,
    const unsigned short* w1p, const float* b1, const float* g, const float* bt,
    const unsigned short* w2p, const float* b2,
    const unsigned short* c1p, const float* cb1, const float* cw2, const float* cb2,
    float* aggr, float* xacc)
{
    __shared__ __align__(16) char sbuf[64 * (K1S * 32 + 8) * 2 + 5632];
    edge_body<F, K1S, float>(sbuf, blockIdx.x, order, coords, h, src, dst, efeat,
        w1p, b1, g, bt, w2p, b2, c1p, cb1, cw2, cb2, aggr, xacc);
}

__global__ __launch_bounds__(256, 4) void attn_f32mask(
    int nb1,
    const float* h1, const float* qw1, const bf16* k1, const bf16* v1,
    const float* mf1, long mrs1, long mcs1,
    float* pO1, float* pM1, float* pL1, int nrows1, int ncols1, int ns1,
    const float* h2, const float* qw2, const bf16* k2, const bf16* v2,
    const float* mf2, long mrs2, long mcs2,
    float* pO2, float* pM2, float* pL2, int nrows2, int ncols2, int ns2)
{
    __shared__ __align__(16) char sbuf[29696];
    attn_body<1>(sbuf, blockIdx.x, nb1,
        h1, qw1, k1, v1, (const unsigned long long*)0, mf1, mrs1, mcs1,
        pO1, pM1, pL1, nrows1, ncols1, ns1,
        h2, qw2, k2, v2, (const unsigned long long*)0, mf2, mrs2, mcs2,
        pO2, pM2, pL2, nrows2, ncols2, ns2);
}

// ============ node kernel: dual-graph, packed weights, FUSED attention merge ============
// nsm>0: att computed inline from split partials (pO/pM/pL); nsm==0: read att array.
__global__ __launch_bounds__(256, 3) void node_mfma(
    int nbl, int nbn, int nsm1, int nsm2,
    const float* h1, const float* __restrict__ aggr1, const int* __restrict__ cnt1,
    const float* att1, const float* __restrict__ origh1,
    const unsigned short* __restrict__ w1pa, const float* __restrict__ b1a,
    const float* __restrict__ ga, const float* __restrict__ bta,
    const unsigned short* __restrict__ w2pa, const float* __restrict__ b2a, float* out1,
    const float* __restrict__ pOa, const float* __restrict__ pMa, const float* __restrict__ pLa,
    const float* h2, const float* __restrict__ aggr2, const int* __restrict__ cnt2,
    const float* att2, const float* __restrict__ origh2,
    const unsigned short* __restrict__ w1pb, const float* __restrict__ b1b,
    const float* __restrict__ gb, const float* __restrict__ btb,
    const unsigned short* __restrict__ w2pb, const float* __restrict__ b2b, float* out2,
    const float* __restrict__ pOb, const float* __restrict__ pMb, const float* __restrict__ pLb,
    const float* __restrict__ ocl, const float* __restrict__ ccl,
    const float* __restrict__ xaccl, float* __restrict__ outxl,
    const float* __restrict__ ocr, const float* __restrict__ ccr,
    const float* __restrict__ xaccr, float* __restrict__ outxr)
{
    if ((int)blockIdx.x >= nbn) {
        int i = (blockIdx.x - nbn) * 256 + threadIdx.x;
        if (i < N_LIG * 3) {
            int node = i / 3;
            float invc = 1.f / fmaxf((float)cnt1[node], 1.f);
            outxl[i] = 0.25f * ocl[i] + 0.75f * ccl[i] + xaccl[i] * invc;
        } else {
            i -= N_LIG * 3;
            if (i < N_REC * 3) {
                int node = i / 3;
                float invc = 1.f / fmaxf((float)cnt2[node], 1.f);
                outxr[i] = 0.25f * ocr[i] + 0.75f * ccr[i] + xaccr[i] * invc;
            }
        }
        return;
    }

    const float *h, *aggr, *att, *orig_h, *b1, *g, *bt, *b2;
    const float *pO, *pM, *pL;
    const unsigned short *w1p, *w2p;
    const int* cnt;
    float* h_out;
    int n0, nsm, nrows;
    if ((int)blockIdx.x < nbl) {
        h = h1; aggr = aggr1; cnt = cnt1; att = att1; orig_h = origh1;
        w1p = w1pa; b1 = b1a; g = ga; bt = bta; w2p = w2pa; b2 = b2a; h_out = out1;
        pO = pOa; pM = pMa; pL = pLa; nsm = nsm1; nrows = N_LIG;
        n0 = blockIdx.x * 64;
    } else {
        h = h2; aggr = aggr2; cnt = cnt2; att = att2; orig_h = origh2;
        w1p = w1pb; b1 = b1b; g = gb; bt = btb; w2p = w2pb; b2 = b2b; h_out = out2;
        pO = pOb; pM = pMb; pL = pLb; nsm = nsm2; nrows = N_REC;
        n0 = (blockIdx.x - nbl) * 64;
    }

    constexpr int KP = 264;
    __shared__ __align__(16) char smem[64 * KP * 2];
    __shared__ __align__(16) unsigned short h1b[64 * 72];
    __shared__ float sums[256], sums2[256];
    __shared__ float stat_m[64], stat_r[64];
    __shared__ float invc_s[64];
    unsigned short* xb  = (unsigned short*)smem;
    float*          h1f = (float*)smem;

    const int t  = threadIdx.x;
    const int wv = t >> 6;
    const int L  = t & 63;
    const int lm = t & 15;
    const int qd = (t & 63) >> 4;
    const int n  = wv * 16 + lm;

    bfrag8 w1f[8], w2f[2];
    #pragma unroll
    for (int kk = 0; kk < 8; ++kk)
        w1f[kk] = *(const bfrag8*)&w1p[((size_t)(kk * 4 + wv) * 64 + L) * 8];
    #pragma unroll
    for (int kk = 0; kk < 2; ++kk)
        w2f[kk] = *(const bfrag8*)&w2p[((size_t)(kk * 4 + wv) * 64 + L) * 8];
    const float b1n = b1[n], b2n = b2[n];

    if (t < 64) invc_s[t] = 1.f / fmaxf((float)cnt[n0 + t], 1.f);
    __syncthreads();

    // staging: 64 nodes x 4 arrays x 8 chunks(8 floats); arr==2 does fused merge
    #pragma unroll
    for (int it = 0; it < 8; ++it) {
        int idx = t + 256 * it;
        int e   = idx >> 5;
        int c   = idx & 31;
        int arr = c >> 3, ch = (c & 7) * 8;
        unsigned short tmp[8];
        if (arr == 2 && nsm > 0) {
            int row = n0 + e;
            float mstar = -1e30f;
            for (int s = 0; s < nsm; ++s)
                mstar = fmaxf(mstar, pM[(size_t)s * nrows + row]);
            float Lsum = 0.f;
            float O[8] = {0.f, 0.f, 0.f, 0.f, 0.f, 0.f, 0.f, 0.f};
            for (int s = 0; s < nsm; ++s) {
                float w = __expf(pM[(size_t)s * nrows + row] - mstar);
                Lsum += pL[(size_t)s * nrows + row] * w;
                const float* po = pO + ((size_t)s * nrows + row) * 64 + ch;
                float4 a = *(const float4*)po;
                float4 b = *(const float4*)(po + 4);
                O[0] += a.x * w; O[1] += a.y * w; O[2] += a.z * w; O[3] += a.w * w;
                O[4] += b.x * w; O[5] += b.y * w; O[6] += b.z * w; O[7] += b.w * w;
            }
            float inv = 1.f / Lsum;
            #pragma unroll
            for (int j = 0; j < 8; ++j) tmp[j] = (unsigned short)bfbits(O[j] * inv);
        } else {
            const float* sp;
            if      (arr == 0) sp = h      + (size_t)(n0 + e) * 64 + ch;
            else if (arr == 1) sp = aggr   + (size_t)(n0 + e) * 64 + ch;
            else if (arr == 2) sp = att    + (size_t)(n0 + e) * 64 + ch;
            else               sp = orig_h + (size_t)(n0 + e) * 64 + ch;
            float4 a = *(const float4*)sp;
            float4 b = *(const float4*)(sp + 4);
            float s = (arr == 1) ? invc_s[e] : 1.f;
            tmp[0] = (unsigned short)bfbits(a.x * s); tmp[1] = (unsigned short)bfbits(a.y * s);
            tmp[2] = (unsigned short)bfbits(a.z * s); tmp[3] = (unsigned short)bfbits(a.w * s);
            tmp[4] = (unsigned short)bfbits(b.x * s); tmp[5] = (unsigned short)bfbits(b.y * s);
            tmp[6] = (unsigned short)bfbits(b.z * s); tmp[7] = (unsigned short)bfbits(b.w * s);
        }
        *(uint4*)&xb[e * KP + arr * 64 + ch] = *(uint4*)tmp;
    }
    __syncthreads();

    f32x4 acc1[4];
    #pragma unroll
    for (int m = 0; m < 4; ++m) {
        f32x4 acc = {0.f, 0.f, 0.f, 0.f};
        #pragma unroll
        for (int kk = 0; kk < 8; ++kk) {
            bfrag8 a = *(const bfrag8*)&xb[(m * 16 + lm) * KP + kk * 32 + qd * 8];
            acc = __builtin_amdgcn_mfma_f32_16x16x32_bf16(a, w1f[kk], acc, 0, 0, 0);
        }
        acc1[m] = acc;
    }
    __syncthreads();
    #pragma unroll
    for (int m = 0; m < 4; ++m)
        #pragma unroll
        for (int r = 0; r < 4; ++r) {
            int mr = m * 16 + qd * 4 + r;
            float v = acc1[m][r] + b1n;
            v = v > 0.f ? v : 0.01f * v;
            h1f[mr * 68 + n] = v;
        }
    __syncthreads();

    {
        int e = t >> 2, seg = (t & 3) * 16;
        float s1 = 0.f, s2 = 0.f;
        #pragma unroll
        for (int j = 0; j < 16; ++j) {
            float v = h1f[e * 68 + seg + j];
            s1 += v; s2 += v * v;
        }
        sums[t] = s1; sums2[t] = s2;
    }
    __syncthreads();
    if (t < 64) {
        float s1 = sums[4 * t] + sums[4 * t + 1] + sums[4 * t + 2] + sums[4 * t + 3];
        float s2 = sums2[4 * t] + sums2[4 * t + 1] + sums2[4 * t + 2] + sums2[4 * t + 3];
        float mean = s1 * (1.f / 64.f);
        float var = s2 * (1.f / 64.f) - mean * mean;
        stat_m[t] = mean;
        stat_r[t] = rsqrtf(fmaxf(var, 0.f) + 1e-5f);
    }
    __syncthreads();
    for (int idx = t; idx < 4096; idx += 256) {
        int e = idx >> 6, j = idx & 63;
        float v = (h1f[e * 68 + j] - stat_m[e]) * stat_r[e] * g[j] + bt[j];
        h1b[e * 72 + j] = bfbits(v);
    }
    __syncthreads();

    #pragma unroll
    for (int m = 0; m < 4; ++m) {
        f32x4 acc = {0.f, 0.f, 0.f, 0.f};
        #pragma unroll
        for (int kk = 0; kk < 2; ++kk) {
            bfrag8 a = *(const bfrag8*)&h1b[(m * 16 + lm) * 72 + kk * 32 + qd * 8];
            acc = __builtin_amdgcn_mfma_f32_16x16x32_bf16(a, w2f[kk], acc, 0, 0, 0);
        }
        #pragma unroll
        for (int r = 0; r < 4; ++r) {
            int row = n0 + m * 16 + qd * 4 + r;
            float o = acc[r] + b2n;
            float hv = h[(size_t)row * 64 + n];
            h_out[(size_t)row * 64 + n] = 0.5f * o + 0.5f * hv;
        }
    }
}

// ---------------- merge split partials (tier 1 only) ----------------
__global__ __launch_bounds__(64) void attn_merge2(
    const float* __restrict__ pO1, const float* __restrict__ pM1, const float* __restrict__ pL1,
    float* __restrict__ out1, int ns1,
    const float* __restrict__ pO2, const float* __restrict__ pM2, const float* __restrict__ pL2,
    float* __restrict__ out2, int ns2)
{
    int r = blockIdx.x;
    const float *pO, *pM, *pL; float* out; int n_rows, nsplit;
    if (r < N_LIG) { pO = pO1; pM = pM1; pL = pL1; out = out1; n_rows = N_LIG; nsplit = ns1; }
    else { r -= N_LIG; pO = pO2; pM = pM2; pL = pL2; out = out2; n_rows = N_REC; nsplit = ns2; }
    int d = threadIdx.x;
    float mstar = -1e30f;
    for (int s = 0; s < nsplit; ++s) mstar = fmaxf(mstar, pM[(size_t)s * n_rows + r]);
    float L = 0.f, O = 0.f;
    for (int s = 0; s < nsplit; ++s) {
        float w = __expf(pM[(size_t)s * n_rows + r] - mstar);
        L += pL[(size_t)s * n_rows + r] * w;
        O += pO[((size_t)s * n_rows + r) * 64 + d] * w;
    }
    out[(size_t)r * 64 + d] = O / L;
}

// ---------------- per-row attention (tier-2 fallback) ----------------
__global__ __launch_bounds__(256) void attn_row_kernel(
    const float* __restrict__ h, const float* __restrict__ qw,
    const bf16* __restrict__ k, const bf16* __restrict__ v,
    const float* __restrict__ mask, long mrs, long mcs,
    float* __restrict__ out, int n_cols)
{
    int row = blockIdx.x;
    int tid = threadIdx.x;
    extern __shared__ float sc[];
    __shared__ float hrow[64];
    __shared__ float qrow[64];
    __shared__ float red[4];
    __shared__ float opart[4][64];

    if (tid < 64) hrow[tid] = h[(size_t)row * 64 + tid];
    __syncthreads();
    if (tid < 64) {
        float a = 0.f;
        #pragma unroll 8
        for (int i = 0; i < 64; ++i) a += hrow[i] * qw[i * 64 + tid];
        qrow[tid] = a > 0.f ? a : 0.01f * a;
    }
    __syncthreads();

    float lmax = -1e30f;
    for (int c = tid; c < n_cols; c += 256) {
        const bf16* kr = k + (size_t)c * 64;
        float s = 0.f;
        #pragma unroll 8
        for (int i = 0; i < 64; ++i) s += qrow[i] * ldkv(kr, i);
        float m = mask[(size_t)row * mrs + (size_t)c * mcs];
        s = m * s - 1000.f * (1.f - m);
        sc[c] = s;
        lmax = fmaxf(lmax, s);
    }
    #pragma unroll
    for (int o = 32; o > 0; o >>= 1) lmax = fmaxf(lmax, __shfl_xor(lmax, o, 64));
    int wid = tid >> 6;
    if ((tid & 63) == 0) red[wid] = lmax;
    __syncthreads();
    float bmax = fmaxf(fmaxf(red[0], red[1]), fmaxf(red[2], red[3]));
    __syncthreads();

    float lsum = 0.f;
    for (int c = tid; c < n_cols; c += 256) {
        float e = __expf(sc[c] - bmax);
        sc[c] = e;
        lsum += e;
    }
    lsum = wave_sum(lsum);
    if ((tid & 63) == 0) red[wid] = lsum;
    __syncthreads();
    float inv = 1.f / (red[0] + red[1] + red[2] + red[3]);

    int dd = tid & 63;
    float o = 0.f;
    for (int c = wid; c < n_cols; c += 4) o += sc[c] * ldkv(v, (size_t)c * 64 + dd);
    opart[wid][dd] = o;
    __syncthreads();
    if (wid == 0)
        out[(size_t)row * 64 + dd] =
            (opart[0][dd] + opart[1][dd] + opart[2][dd] + opart[3][dd]) * inv;
}

extern "C" void kernel_launch(void* const* d_in, const int* in_sizes, int n_in,
                              void* d_out, int out_size, void* d_ws, size_t ws_size,
                              hipStream_t stream)
{
    const float* coords_lig      = (const float*)d_in[0];
    const float* h_lig           = (const float*)d_in[1];
    const float* orig_h_lig      = (const float*)d_in[2];
    const float* orig_coords_lig = (const float*)d_in[3];
    const float* coords_rec      = (const float*)d_in[4];
    const float* h_rec           = (const float*)d_in[5];
    const float* orig_h_rec      = (const float*)d_in[6];
    const float* orig_coords_rec = (const float*)d_in[7];
    const int* lig_src   = (const int*)d_in[8];
    const int* lig_dst   = (const int*)d_in[9];
    const float* lig_efeat = (const float*)d_in[10];
    const int* rec_src   = (const int*)d_in[11];
    const int* rec_dst   = (const int*)d_in[12];
    const float* rec_efeat = (const float*)d_in[13];
    const float* mask      = (const float*)d_in[14];
    const float *lig_em_w1 = (const float*)d_in[15], *lig_em_b1 = (const float*)d_in[16];
    const float *lig_em_g  = (const float*)d_in[17], *lig_em_bt = (const float*)d_in[18];
    const float *lig_em_w2 = (const float*)d_in[19], *lig_em_b2 = (const float*)d_in[20];
    const float *rec_em_w1 = (const float*)d_in[21], *rec_em_b1 = (const float*)d_in[22];
    const float *rec_em_g  = (const float*)d_in[23], *rec_em_bt = (const float*)d_in[24];
    const float *rec_em_w2 = (const float*)d_in[25], *rec_em_b2 = (const float*)d_in[26];
    const float *lig_cm_w1 = (const float*)d_in[27], *lig_cm_b1 = (const float*)d_in[28];
    const float *lig_cm_w2 = (const float*)d_in[29], *lig_cm_b2 = (const float*)d_in[30];
    const float *rec_cm_w1 = (const float*)d_in[31], *rec_cm_b1 = (const float*)d_in[32];
    const float *rec_cm_w2 = (const float*)d_in[33], *rec_cm_b2 = (const float*)d_in[34];
    const float *q_lig_w = (const float*)d_in[35], *k_lig_w = (const float*)d_in[36];
    const float *v_lig_w = (const float*)d_in[37], *q_rec_w = (const float*)d_in[38];
    const float *k_rec_w = (const float*)d_in[39], *v_rec_w = (const float*)d_in[40];
    const float *lig_nm_w1 = (const float*)d_in[41], *lig_nm_b1 = (const float*)d_in[42];
    const float *lig_nm_g  = (const float*)d_in[43], *lig_nm_bt = (const float*)d_in[44];
    const float *lig_nm_w2 = (const float*)d_in[45], *lig_nm_b2 = (const float*)d_in[46];
    const float *rec_nm_w1 = (const float*)d_in[47], *rec_nm_b1 = (const float*)d_in[48];
    const float *rec_nm_g  = (const float*)d_in[49], *rec_nm_bt = (const float*)d_in[50];
    const float *rec_nm_w2 = (const float*)d_in[51], *rec_nm_b2 = (const float*)d_in[52];

    char* wsb = (char*)d_ws;
    float* aggr_l = (float*)(wsb + 16);
    float* aggr_r = aggr_l + (size_t)N_LIG * 64;
    float* xacc_l = aggr_r + (size_t)N_REC * 64;
    float* xacc_r = xacc_l + (size_t)N_LIG * 3;
    int* counts_l = (int*)(xacc_r + (size_t)N_REC * 3);
    int* counts_r = counts_l + N_LIG;
    int* cursor_l = counts_r + N_REC;
    int* cursor_r = cursor_l + N_LIG;
    int* order_l  = cursor_r + N_REC;
    int* order_r  = order_l + E_LIG;
    unsigned short* p_rec1  = (unsigned short*)(order_r + E_REC);
    unsigned short* p_lig1  = p_rec1 + 6 * 2048;
    unsigned short* p_rec2  = p_lig1 + 5 * 2048;
    unsigned short* p_lig2  = p_rec2 + 2 * 2048;
    unsigned short* pc_rec1 = p_lig2 + 2 * 2048;
    unsigned short* pc_lig1 = pc_rec1 + 2 * 2048;
    unsigned short* pn_rec1 = pc_lig1 + 2 * 2048;
    unsigned short* pn_lig1 = pn_rec1 + 8 * 2048;
    unsigned short* pn_rec2 = pn_lig1 + 8 * 2048;
    unsigned short* pn_lig2 = pn_rec2 + 2 * 2048;
    char* kv_base = (char*)(pn_lig2 + 2 * 2048);
    const size_t core_b = (size_t)(kv_base - wsb);
    const size_t kv_b = (size_t)(N_LIG + N_REC) * 64 * 2 * 2;

    const size_t mq1_n = (size_t)(N_REC / 64) * N_LIG;
    const size_t mq2_n = (size_t)(N_LIG / 64) * N_REC;
    const size_t mq_all_b = (mq1_n + mq2_n) * 8;
    const size_t mir_b = (size_t)(N_LIG + N_REC) * 64 * 2
                       + ((size_t)E_LIG * F_LIGc + (size_t)E_REC * F_RECc) * 2;

    const size_t part_b_hi = ((size_t)8 * N_LIG * 64 + (size_t)4 * N_REC * 64) * 4
                           + ((size_t)8 * N_LIG + (size_t)4 * N_REC) * 2 * 4;
    const size_t part_b_lo = ((size_t)4 * N_LIG * 64 + (size_t)2 * N_REC * 64) * 4
                           + ((size_t)4 * N_LIG + (size_t)2 * N_REC) * 2 * 4;

    int tier, ns1, ns2;
    size_t part_b;
    if (ws_size >= core_b + kv_b + part_b_hi + mq_all_b + mir_b) {
        tier = 0; ns1 = 8; ns2 = 4; part_b = part_b_hi;
    } else if (ws_size >= core_b + kv_b + part_b_lo) {
        tier = 1; ns1 = 4; ns2 = 2; part_b = part_b_lo;
    } else {
        tier = 2; ns1 = 4; ns2 = 2; part_b = part_b_lo;
    }

    bf16* kb_l = (bf16*)kv_base;
    bf16* vb_l = kb_l + (size_t)N_LIG * 64;
    bf16* kb_r = vb_l + (size_t)N_LIG * 64;
    bf16* vb_r = kb_r + (size_t)N_REC * 64;
    float* pO1 = (float*)(kv_base + kv_b);
    float* pO2 = pO1 + (size_t)ns1 * N_LIG * 64;
    float* pM1 = pO2 + (size_t)ns2 * N_REC * 64;
    float* pL1 = pM1 + (size_t)ns1 * N_LIG;
    float* pM2 = pL1 + (size_t)ns1 * N_LIG;
    float* pL2 = pM2 + (size_t)ns2 * N_REC;
    unsigned long long* mqb  = (unsigned long long*)(kv_base + kv_b + part_b);
    unsigned long long* mqbT = mqb + mq1_n;
    bf16* hb_l  = (bf16*)(mqbT + mq2_n);
    bf16* hb_r  = hb_l + (size_t)N_LIG * 64;
    bf16* efb_l = hb_r + (size_t)N_REC * 64;
    bf16* efb_r = efb_l + (size_t)E_LIG * F_LIGc;

    float* out = (float*)d_out;
    float* x_lig_o = out;
    float* h_lig_o = out + 12288;
    float* x_rec_o = out + 274432;
    float* h_rec_o = out + 299008;

    const int nb1 = (N_LIG / 64) * ns1;
    const int nb2 = (N_REC / 64) * ns2;

    if (tier == 0) {
        zero_kernel<<<(N_LIG + N_REC + 255) / 256, 256, 0, stream>>>(
            (float*)counts_l, N_LIG + N_REC);
        prep_kernel<<<NB_PREP, 256, 0, stream>>>(
            mask, mqb, mqbT,
            h_lig, hb_l, h_rec, hb_r, lig_efeat, efb_l, rec_efeat, efb_r,
            k_lig_w, v_lig_w, k_rec_w, v_rec_w, kb_l, vb_l, kb_r, vb_r,
            aggr_l,
            lig_dst, rec_dst, counts_l, counts_r,
            rec_em_w1, lig_em_w1, rec_em_w2, lig_em_w2, rec_cm_w1, lig_cm_w1,
            rec_nm_w1, lig_nm_w1, rec_nm_w2, lig_nm_w2,
            p_rec1, p_lig1, p_rec2, p_lig2, pc_rec1, pc_lig1,
            pn_rec1, pn_lig1, pn_rec2, pn_lig2);
        scan2_kernel<<<2, 256, 0, stream>>>(counts_l, cursor_l, counts_r, cursor_r);
        scatter2_kernel<<<(E_LIG + E_REC) / 256, 256, 0, stream>>>(
            lig_dst, rec_dst, cursor_l, cursor_r, order_l, order_r);

        // fused attn (1024, LJF first) + edge_rec (4096) + edge_lig (1024)
        mega_kernel<<<nb1 + nb2 + (E_LIG + E_REC) / 64, 256, 0, stream>>>(
            nb1,
            h_lig, q_lig_w, kb_r, vb_r, mqb, pO1, pM1, pL1, N_LIG, N_REC, ns1,
            h_rec, q_rec_w, kb_l, vb_l, mqbT, pO2, pM2, pL2, N_REC, N_LIG, ns2,
            order_r, coords_rec, hb_r, rec_src, rec_dst, efb_r,
            p_rec1, rec_em_b1, rec_em_g, rec_em_bt, p_rec2, rec_em_b2,
            pc_rec1, rec_cm_b1, rec_cm_w2, rec_cm_b2, aggr_r, xacc_r,
            order_l, coords_lig, hb_l, lig_src, lig_dst, efb_l,
            p_lig1, lig_em_b1, lig_em_g, lig_em_bt, p_lig2, lig_em_b2,
            pc_lig1, lig_cm_b1, lig_cm_w2, lig_cm_b2, aggr_l, xacc_l);
        // NO merge launch: node_mfma does the split-merge inline (nsm>0)
    } else {
        zero_kernel<<<(N_ZERO + 255) / 256, 256, 0, stream>>>(aggr_l, N_ZERO);
        pack_frags<<<NB_PACK, 256, 0, stream>>>(
            rec_em_w1, lig_em_w1, rec_em_w2, lig_em_w2, rec_cm_w1, lig_cm_w1,
            rec_nm_w1, lig_nm_w1, rec_nm_w2, lig_nm_w2,
            p_rec1, p_lig1, p_rec2, p_lig2, pc_rec1, pc_lig1,
            pn_rec1, pn_lig1, pn_rec2, pn_lig2);
        hist2_kernel<<<(E_LIG + E_REC) / 256, 256, 0, stream>>>(
            lig_dst, rec_dst, counts_l, counts_r);
        scan2_kernel<<<2, 256, 0, stream>>>(counts_l, cursor_l, counts_r, cursor_r);
        scatter2_kernel<<<(E_LIG + E_REC) / 256, 256, 0, stream>>>(
            lig_dst, rec_dst, cursor_l, cursor_r, order_l, order_r);
        kv_proj_kernel<<<(2 * (N_LIG + N_REC)) / 4, 256, 0, stream>>>(
            h_lig, h_rec, k_lig_w, v_lig_w, k_rec_w, v_rec_w,
            kb_l, vb_l, kb_r, vb_r);

        edge_mfma_f<F_LIGc, 5><<<E_LIG / 64, 256, 0, stream>>>(
            order_l, coords_lig, h_lig, lig_src, lig_dst, lig_efeat,
            p_lig1, lig_em_b1, lig_em_g, lig_em_bt, p_lig2, lig_em_b2,
            pc_lig1, lig_cm_b1, lig_cm_w2, lig_cm_b2, aggr_l, xacc_l);
        edge_mfma_f<F_RECc, 6><<<E_REC / 64, 256, 0, stream>>>(
            order_r, coords_rec, h_rec, rec_src, rec_dst, rec_efeat,
            p_rec1, rec_em_b1, rec_em_g, rec_em_bt, p_rec2, rec_em_b2,
            pc_rec1, rec_cm_b1, rec_cm_w2, rec_cm_b2, aggr_r, xacc_r);
        if (tier == 1) {
            attn_f32mask<<<nb1 + nb2, 256, 0, stream>>>(
                nb1,
                h_lig, q_lig_w, kb_r, vb_r, mask, (long)N_REC, 1L,
                pO1, pM1, pL1, N_LIG, N_REC, ns1,
                h_rec, q_rec_w, kb_l, vb_l, mask, 1L, (long)N_REC,
                pO2, pM2, pL2, N_REC, N_LIG, ns2);
            attn_merge2<<<N_LIG + N_REC, 64, 0, stream>>>(
                pO1, pM1, pL1, h_lig_o, ns1, pO2, pM2, pL2, h_rec_o, ns2);
        } else {
            attn_row_kernel<<<N_LIG, 256, N_REC * sizeof(float), stream>>>(
                h_lig, q_lig_w, kb_r, vb_r, mask, (long)N_REC, 1L, h_lig_o, N_REC);
            attn_row_kernel<<<N_REC, 256, N_LIG * sizeof(float), stream>>>(
                h_rec, q_rec_w, kb_l, vb_l, mask, 1L, (long)N_REC, h_rec_o, N_LIG);
        }
    }

    // node updates (192 blocks; fused attn-merge in tier 0) + coord blocks
    const int nbn = N_LIG / 64 + N_REC / 64;
    const int nbc = ((N_LIG + N_REC) * 3 + 255) / 256;
    const int nsm1 = (tier == 0) ? ns1 : 0;
    const int nsm2 = (tier == 0) ? ns2 : 0;
    node_mfma<<<nbn + nbc, 256, 0, stream>>>(
        N_LIG / 64, nbn, nsm1, nsm2,
        h_lig, aggr_l, counts_l, h_lig_o, orig_h_lig,
        pn_lig1, lig_nm_b1, lig_nm_g, lig_nm_bt, pn_lig2, lig_nm_b2, h_lig_o,
        pO1, pM1, pL1,
        h_rec, aggr_r, counts_r, h_rec_o, orig_h_rec,
        pn_rec1, rec_nm_b1, rec_nm_g, rec_nm_bt, pn_rec2, rec_nm_b2, h_rec_o,
        pO2, pM2, pL2,
        orig_coords_lig, coords_lig, xacc_l, x_lig_o,
        orig_coords_rec, coords_rec, xacc_r, x_rec_o);
}

// Round 11
// 546.255 us; speedup vs baseline: 1.0403x; 1.0403x over previous
//
#include <hip/hip_runtime.h>
#include <hip/hip_bf16.h>

typedef __hip_bfloat16 bf16;
typedef __attribute__((ext_vector_type(8))) short bfrag8;
typedef __attribute__((ext_vector_type(4))) float f32x4;

#define N_LIG 4096
#define N_REC 8192
#define E_LIG 65536
#define E_REC 262144
#define F_LIGc 15
#define F_RECc 27

__device__ __forceinline__ float ldkv(const float* p, size_t i) { return p[i]; }
__device__ __forceinline__ float ldkv(const bf16* p, size_t i) { return __bfloat162float(p[i]); }
__device__ __forceinline__ short bfbits(float x) {
    bf16 b = __float2bfloat16(x);
    return *(short*)&b;
}
__device__ __forceinline__ unsigned short stg(const float* p, size_t i) {
    return (unsigned short)bfbits(p[i]);
}
__device__ __forceinline__ unsigned short stg(const bf16* p, size_t i) {
    return *(const unsigned short*)(p + i);
}
__device__ __forceinline__ void stage16(unsigned short* d, const bf16* s) {
    *(uint4*)d = *(const uint4*)s;
}
__device__ __forceinline__ void stage16(unsigned short* d, const float* s) {
    float4 a = *(const float4*)s;
    float4 b = *(const float4*)(s + 4);
    unsigned short tmp[8] = {
        (unsigned short)bfbits(a.x), (unsigned short)bfbits(a.y),
        (unsigned short)bfbits(a.z), (unsigned short)bfbits(a.w),
        (unsigned short)bfbits(b.x), (unsigned short)bfbits(b.y),
        (unsigned short)bfbits(b.z), (unsigned short)bfbits(b.w)};
    *(uint4*)d = *(uint4*)tmp;
}
__device__ __forceinline__ void cv4(bf16* d, const float* s) {
    float4 v = *(const float4*)s;
    unsigned short tmp[4] = {
        (unsigned short)bfbits(v.x), (unsigned short)bfbits(v.y),
        (unsigned short)bfbits(v.z), (unsigned short)bfbits(v.w)};
    *(uint2*)d = *(uint2*)tmp;
}

// XOR-swizzled LDS index (shorts): 64-col rows, 16B blocks permuted per-row.
__device__ __forceinline__ int swz(int row, int col) {
    return (row << 6) + ((((col >> 3) ^ row ^ (row >> 3)) & 7) << 3) + (col & 7);
}

__constant__ float c_inv_sigma[15] = {
    1.0f, 0.6666666667f, 0.4444444444f, 0.2962962963f, 0.1975308642f,
    0.1316872428f, 0.08779149520f, 0.05852766346f, 0.03901844231f,
    0.02601229487f, 0.01734152992f, 0.01156101994f, 0.007707346628f,
    0.005138231085f, 0.003425487390f};

__device__ __forceinline__ float wave_sum(float v) {
    #pragma unroll
    for (int o = 32; o > 0; o >>= 1) v += __shfl_xor(v, o, 64);
    return v;
}
__device__ __forceinline__ float quad_max(float v) {
    v = fmaxf(v, __shfl_xor(v, 1)); v = fmaxf(v, __shfl_xor(v, 2));
    v = fmaxf(v, __shfl_xor(v, 4)); v = fmaxf(v, __shfl_xor(v, 8));
    return v;
}

// ---------------- reusable prep bodies ----------------
__device__ __forceinline__ void pack_body(
    int b, int t,
    const float* w_rec1, const float* w_lig1, const float* w_rec2, const float* w_lig2,
    const float* c_rec1, const float* c_lig1,
    const float* n_rec1, const float* n_lig1, const float* n_rec2, const float* n_lig2,
    unsigned short* p_rec1, unsigned short* p_lig1,
    unsigned short* p_rec2, unsigned short* p_lig2,
    unsigned short* pc_rec1, unsigned short* pc_lig1,
    unsigned short* pn_rec1, unsigned short* pn_lig1,
    unsigned short* pn_rec2, unsigned short* pn_lig2)
{
    const float* src; unsigned short* dst; int kk, IN;
    if (b < 6)       { src = w_rec1; dst = p_rec1;  kk = b;      IN = 170; }
    else if (b < 11) { src = w_lig1; dst = p_lig1;  kk = b - 6;  IN = 158; }
    else if (b < 13) { src = w_rec2; dst = p_rec2;  kk = b - 11; IN = 64; }
    else if (b < 15) { src = w_lig2; dst = p_lig2;  kk = b - 13; IN = 64; }
    else if (b < 17) { src = c_rec1; dst = pc_rec1; kk = b - 15; IN = 64; }
    else if (b < 19) { src = c_lig1; dst = pc_lig1; kk = b - 17; IN = 64; }
    else if (b < 27) { src = n_rec1; dst = pn_rec1; kk = b - 19; IN = 256; }
    else if (b < 35) { src = n_lig1; dst = pn_lig1; kk = b - 27; IN = 256; }
    else if (b < 37) { src = n_rec2; dst = pn_rec2; kk = b - 35; IN = 64; }
    else             { src = n_lig2; dst = pn_lig2; kk = b - 37; IN = 64; }
    int wv = t >> 6, L = t & 63, lm = L & 15, qd = L >> 4;
    int n = wv * 16 + lm;
    unsigned short tmp[8];
    #pragma unroll
    for (int j = 0; j < 8; ++j) {
        int k = kk * 32 + qd * 8 + j;
        tmp[j] = (k < IN) ? (unsigned short)bfbits(src[k * 64 + n]) : (unsigned short)0;
    }
    *(uint4*)&dst[((size_t)(kk * 4 + wv) * 64 + L) * 8] = *(uint4*)tmp;
}

__device__ __forceinline__ void kv_body(
    int job, int j,
    const float* h_lig, const float* h_rec,
    const float* kwl, const float* vwl, const float* kwr, const float* vwr,
    bf16* kbl, bf16* vbl, bf16* kbr, bf16* vbr)
{
    const float *h, *w; bf16* out; int node, do_l;
    if (job < N_LIG)                  { h = h_lig; w = kwl; out = kbl; node = job;                     do_l = 1; }
    else if (job < 2 * N_LIG)         { h = h_lig; w = vwl; out = vbl; node = job - N_LIG;             do_l = 0; }
    else if (job < 2 * N_LIG + N_REC) { h = h_rec; w = kwr; out = kbr; node = job - 2 * N_LIG;         do_l = 1; }
    else                              { h = h_rec; w = vwr; out = vbr; node = job - 2 * N_LIG - N_REC; do_l = 0; }
    float xv = h[(size_t)node * 64 + j];
    float acc = 0.f;
    #pragma unroll
    for (int i = 0; i < 64; ++i) acc += __shfl(xv, i, 64) * w[i * 64 + j];
    if (do_l) acc = acc > 0.f ? acc : 0.01f * acc;
    out[(size_t)node * 64 + j] = __float2bfloat16(acc);
}

__device__ __forceinline__ void mask_body(
    unsigned char* tr, unsigned char* tc, int bx, int by, int t,
    const float* mask, unsigned long long* mq, unsigned long long* mqT, int R, int C)
{
    int r0 = by * 64, c0 = bx * 64;
    int cs = (t & 15) * 4;
    #pragma unroll
    for (int rr = 0; rr < 4; ++rr) {
        int r = (t >> 4) + rr * 16;
        const float* mp = &mask[(size_t)(r0 + r) * C + c0 + cs];
        unsigned char b0 = mp[0] != 0.f, b1 = mp[1] != 0.f;
        unsigned char b2 = mp[2] != 0.f, b3 = mp[3] != 0.f;
        tr[r * 68 + cs + 0] = b0; tr[r * 68 + cs + 1] = b1;
        tr[r * 68 + cs + 2] = b2; tr[r * 68 + cs + 3] = b3;
        tc[(cs + 0) * 68 + r] = b0; tc[(cs + 1) * 68 + r] = b1;
        tc[(cs + 2) * 68 + r] = b2; tc[(cs + 3) * 68 + r] = b3;
    }
    __syncthreads();
    if (t < 128) {
        const unsigned* p = (t < 64) ? (const unsigned*)&tr[t * 68]
                                     : (const unsigned*)&tc[(t - 64) * 68];
        unsigned lo = 0, hi = 0;
        #pragma unroll
        for (int i = 0; i < 8; ++i)
            lo |= (((p[i] & 0x01010101u) * 0x01020408u) >> 24 & 0xFu) << (4 * i);
        #pragma unroll
        for (int i = 8; i < 16; ++i)
            hi |= (((p[i] & 0x01010101u) * 0x01020408u) >> 24 & 0xFu) << (4 * (i - 8));
        unsigned long long w = (unsigned long long)lo | ((unsigned long long)hi << 32);
        if (t < 64) mq[(size_t)(c0 >> 6) * R + r0 + t] = w;
        else        mqT[(size_t)(r0 >> 6) * C + c0 + (t - 64)] = w;
    }
}

// ============ fused prep kernel (tier 0): mask + cvt(x4) + kv + zeroA + hist + pack ============
#define NB_MASK   ((N_REC / 64) * (N_LIG / 64))                                   // 8192
#define N_CVT     (N_LIG * 64 + N_REC * 64 + E_LIG * F_LIGc + E_REC * F_RECc)     // 8847360
#define NB_CVT4   (N_CVT / 1024)                                                   // 8640
#define NB_KV     (2 * (N_LIG + N_REC) / 4)                                        // 6144
#define N_ZEROA   (N_LIG * 64 + N_REC * 64 + N_LIG * 3 + N_REC * 3)                // 823296
#define NB_ZEROA  (N_ZEROA / 256)                                                  // 3216
#define N_ZERO    (N_ZEROA + N_LIG + N_REC)                                        // full (tier1/2)
#define NB_HIST   ((E_LIG + E_REC) / 256)                                          // 1280
#define NB_PACK   39
#define NB_PREP   (NB_MASK + NB_CVT4 + NB_KV + NB_ZEROA + NB_HIST + NB_PACK)

__global__ __launch_bounds__(256) void prep_kernel(
    const float* __restrict__ mask, unsigned long long* __restrict__ mq,
    unsigned long long* __restrict__ mqT,
    const float* __restrict__ h_lig, bf16* __restrict__ hb_l,
    const float* __restrict__ h_rec, bf16* __restrict__ hb_r,
    const float* __restrict__ ef_l, bf16* __restrict__ efb_l,
    const float* __restrict__ ef_r, bf16* __restrict__ efb_r,
    const float* __restrict__ kwl, const float* __restrict__ vwl,
    const float* __restrict__ kwr, const float* __restrict__ vwr,
    bf16* __restrict__ kbl, bf16* __restrict__ vbl,
    bf16* __restrict__ kbr, bf16* __restrict__ vbr,
    float* __restrict__ zp,
    const int* __restrict__ dl, const int* __restrict__ dr,
    int* __restrict__ cl, int* __restrict__ cr,
    const float* w_rec1, const float* w_lig1, const float* w_rec2, const float* w_lig2,
    const float* c_rec1, const float* c_lig1,
    const float* n_rec1, const float* n_lig1, const float* n_rec2, const float* n_lig2,
    unsigned short* p_rec1, unsigned short* p_lig1,
    unsigned short* p_rec2, unsigned short* p_lig2,
    unsigned short* pc_rec1, unsigned short* pc_lig1,
    unsigned short* pn_rec1, unsigned short* pn_lig1,
    unsigned short* pn_rec2, unsigned short* pn_lig2)
{
    __shared__ unsigned char tr[64 * 68];
    __shared__ unsigned char tc[64 * 68];
    int b = blockIdx.x, t = threadIdx.x;
    if (b < NB_MASK) {
        mask_body(tr, tc, b & 127, b >> 7, t, mask, mq, mqT, N_LIG, N_REC);
        return;
    }
    b -= NB_MASK;
    if (b < NB_CVT4) {
        int i = (b * 256 + t) * 4;
        if (i < N_LIG * 64) { cv4(hb_l + i, h_lig + i); return; }
        i -= N_LIG * 64;
        if (i < N_REC * 64) { cv4(hb_r + i, h_rec + i); return; }
        i -= N_REC * 64;
        if (i < E_LIG * F_LIGc) { cv4(efb_l + i, ef_l + i); return; }
        i -= E_LIG * F_LIGc;
        cv4(efb_r + i, ef_r + i);
        return;
    }
    b -= NB_CVT4;
    if (b < NB_KV) {
        kv_body(b * 4 + (t >> 6), t & 63, h_lig, h_rec, kwl, vwl, kwr, vwr,
                kbl, vbl, kbr, vbr);
        return;
    }
    b -= NB_KV;
    if (b < NB_ZEROA) {
        zp[b * 256 + t] = 0.f;
        return;
    }
    b -= NB_ZEROA;
    if (b < NB_HIST) {
        int i = b * 256 + t;
        if (i < E_LIG) atomicAdd(&cl[dl[i]], 1);
        else atomicAdd(&cr[dr[i - E_LIG]], 1);
        return;
    }
    b -= NB_HIST;
    pack_body(b, t, w_rec1, w_lig1, w_rec2, w_lig2, c_rec1, c_lig1,
              n_rec1, n_lig1, n_rec2, n_lig2,
              p_rec1, p_lig1, p_rec2, p_lig2, pc_rec1, pc_lig1,
              pn_rec1, pn_lig1, pn_rec2, pn_lig2);
}

// ---------------- standalone prep kernels ----------------
__global__ void zero_kernel(float* __restrict__ p, int n) {
    int i = blockIdx.x * blockDim.x + threadIdx.x;
    if (i < n) p[i] = 0.f;
}
__global__ void hist2_kernel(const int* __restrict__ dl, const int* __restrict__ dr,
                             int* __restrict__ cl, int* __restrict__ cr) {
    int i = blockIdx.x * 256 + threadIdx.x;
    if (i < E_LIG) { atomicAdd(&cl[dl[i]], 1); return; }
    i -= E_LIG;
    if (i < E_REC) atomicAdd(&cr[dr[i]], 1);
}
__global__ __launch_bounds__(256) void pack_frags(
    const float* w_rec1, const float* w_lig1, const float* w_rec2, const float* w_lig2,
    const float* c_rec1, const float* c_lig1,
    const float* n_rec1, const float* n_lig1, const float* n_rec2, const float* n_lig2,
    unsigned short* p_rec1, unsigned short* p_lig1,
    unsigned short* p_rec2, unsigned short* p_lig2,
    unsigned short* pc_rec1, unsigned short* pc_lig1,
    unsigned short* pn_rec1, unsigned short* pn_lig1,
    unsigned short* pn_rec2, unsigned short* pn_lig2)
{
    pack_body(blockIdx.x, threadIdx.x, w_rec1, w_lig1, w_rec2, w_lig2, c_rec1, c_lig1,
              n_rec1, n_lig1, n_rec2, n_lig2,
              p_rec1, p_lig1, p_rec2, p_lig2, pc_rec1, pc_lig1,
              pn_rec1, pn_lig1, pn_rec2, pn_lig2);
}
__global__ __launch_bounds__(256) void kv_proj_kernel(
    const float* __restrict__ h_lig, const float* __restrict__ h_rec,
    const float* __restrict__ kwl, const float* __restrict__ vwl,
    const float* __restrict__ kwr, const float* __restrict__ vwr,
    bf16* __restrict__ kbl, bf16* __restrict__ vbl,
    bf16* __restrict__ kbr, bf16* __restrict__ vbr)
{
    kv_body(blockIdx.x * 4 + (threadIdx.x >> 6), threadIdx.x & 63,
            h_lig, h_rec, kwl, vwl, kwr, vwr, kbl, vbl, kbr, vbr);
}

__global__ __launch_bounds__(256) void scan2_kernel(
    const int* __restrict__ cl, int* __restrict__ curl,
    const int* __restrict__ cr, int* __restrict__ curr)
{
    const int* counts = blockIdx.x ? cr : cl;
    int* cursor = blockIdx.x ? curr : curl;
    int n = blockIdx.x ? N_REC : N_LIG;
    __shared__ int part[256];
    int t = threadIdx.x;
    int c = n / 256;
    int base = t * c;
    int s = 0;
    for (int i = 0; i < c; ++i) s += counts[base + i];
    part[t] = s;
    __syncthreads();
    for (int o = 1; o < 256; o <<= 1) {
        int u = (t >= o) ? part[t - o] : 0;
        __syncthreads();
        part[t] += u;
        __syncthreads();
    }
    int run = part[t] - s;
    for (int i = 0; i < c; ++i) {
        cursor[base + i] = run;
        run += counts[base + i];
    }
}

__global__ void scatter2_kernel(const int* __restrict__ dl, const int* __restrict__ dr,
                                int* __restrict__ curl, int* __restrict__ curr,
                                int* __restrict__ ordl, int* __restrict__ ordr) {
    int i = blockIdx.x * 256 + threadIdx.x;
    if (i < E_LIG) { ordl[atomicAdd(&curl[dl[i]], 1)] = i; return; }
    i -= E_LIG;
    if (i < E_REC) ordr[atomicAdd(&curr[dr[i]], 1)] = i;
}

// ============ edge body (shared-buffer carve-out) ============
template <int F, int K1S, typename HT>
__device__ __forceinline__ void edge_body(
    char* sbuf, int ebid,
    const int* __restrict__ order,
    const float* __restrict__ coords, const HT* __restrict__ h,
    const int* __restrict__ src, const int* __restrict__ dst,
    const HT* __restrict__ efeat,
    const unsigned short* __restrict__ w1p, const float* __restrict__ b1,
    const float* __restrict__ g, const float* __restrict__ bt,
    const unsigned short* __restrict__ w2p, const float* __restrict__ b2,
    const unsigned short* __restrict__ c1p, const float* __restrict__ cb1,
    const float* __restrict__ cw2, const float* __restrict__ cb2,
    float* __restrict__ aggr, float* __restrict__ xacc)
{
    constexpr int IN = 143 + F;
    constexpr int KP = K1S * 32 + 8;
    constexpr int XB = 64 * KP * 2;
    static_assert(XB >= 64 * 68 * 4, "msgf f32 alias must fit in xb");
    static_assert(XB >= 64 * 72 * 2, "h1b alias must fit in xb");
    unsigned short* xb   = (unsigned short*)sbuf;
    unsigned short* h1b  = (unsigned short*)sbuf;
    float*          msgf = (float*)sbuf;
    float* wsum1   = (float*)(sbuf + XB);
    float* wsum2   = (float*)(sbuf + XB + 1024);
    float* stat_m  = (float*)(sbuf + XB + 2048);
    float* stat_r  = (float*)(sbuf + XB + 2304);
    float* coefp   = (float*)(sbuf + XB + 2560);
    float* coef_all= (float*)(sbuf + XB + 3584);
    int*   srcs    = (int*)(sbuf + XB + 3840);
    int*   dsts    = (int*)(sbuf + XB + 4096);
    int*   ords    = (int*)(sbuf + XB + 4352);
    float* xr_s    = (float*)(sbuf + XB + 4608);
    float* d2s     = (float*)(sbuf + XB + 5376);

    const int t  = threadIdx.x;
    const int wv = t >> 6;
    const int L  = t & 63;
    const int lm = L & 15;
    const int qd = L >> 4;
    const int e0 = ebid * 64;
    const int n  = wv * 16 + lm;

    bfrag8 w1f[K1S], w2f[2];
    #pragma unroll
    for (int kk = 0; kk < K1S; ++kk)
        w1f[kk] = *(const bfrag8*)&w1p[((size_t)(kk * 4 + wv) * 64 + L) * 8];
    #pragma unroll
    for (int kk = 0; kk < 2; ++kk)
        w2f[kk] = *(const bfrag8*)&w2p[((size_t)(kk * 4 + wv) * 64 + L) * 8];
    const float b1n = b1[n], b2n = b2[n], cb1n = cb1[n], cw2n = cw2[n];
    const float gn = g[n], btn = bt[n];

    if (t < 64) {
        int e = order[e0 + t];
        int s = src[e], d = dst[e];
        ords[t] = e; srcs[t] = s; dsts[t] = d;
        float x0 = coords[s * 3 + 0] - coords[d * 3 + 0];
        float x1 = coords[s * 3 + 1] - coords[d * 3 + 1];
        float x2 = coords[s * 3 + 2] - coords[d * 3 + 2];
        xr_s[t * 3 + 0] = x0; xr_s[t * 3 + 1] = x1; xr_s[t * 3 + 2] = x2;
        d2s[t] = x0 * x0 + x1 * x1 + x2 * x2;
    }
    __syncthreads();

    #pragma unroll
    for (int u = 0; u < 4; ++u) {
        int idx = t + 256 * u;
        int e = idx >> 4, c = idx & 15;
        int node = (c < 8) ? srcs[e] : dsts[e];
        stage16(&xb[e * KP + c * 8], h + (size_t)node * 64 + (c & 7) * 8);
    }
    for (int idx = t; idx < 64 * F; idx += 256) {
        int e = idx / F, f = idx - e * F;
        xb[e * KP + 128 + f] = stg(efeat, (size_t)ords[e] * F + f);
    }
    for (int idx = t; idx < 64 * 15; idx += 256) {
        int e = idx / 15, s5 = idx - e * 15;
        xb[e * KP + 128 + F + s5] = bfbits(__expf(-d2s[e] * c_inv_sigma[s5]));
    }
    {
        constexpr int PER = K1S * 32 - IN;
        for (int idx = t; idx < 64 * PER; idx += 256) {
            int e = idx / PER, k = idx - e * PER;
            xb[e * KP + IN + k] = 0;
        }
    }
    __syncthreads();

    // ---- GEMM 1 + bias/lrelu + LN partial sums via shfl ----
    float vreg[4][4];
    #pragma unroll
    for (int m = 0; m < 4; ++m) {
        f32x4 acc = {0.f, 0.f, 0.f, 0.f};
        #pragma unroll
        for (int kk = 0; kk < K1S; ++kk) {
            bfrag8 a = *(const bfrag8*)&xb[(m * 16 + lm) * KP + kk * 32 + qd * 8];
            acc = __builtin_amdgcn_mfma_f32_16x16x32_bf16(a, w1f[kk], acc, 0, 0, 0);
        }
        #pragma unroll
        for (int r = 0; r < 4; ++r) {
            float v = acc[r] + b1n;
            v = v > 0.f ? v : 0.01f * v;
            vreg[m][r] = v;
            float a1 = v, a2 = v * v;
            a1 += __shfl_xor(a1, 1); a2 += __shfl_xor(a2, 1);
            a1 += __shfl_xor(a1, 2); a2 += __shfl_xor(a2, 2);
            a1 += __shfl_xor(a1, 4); a2 += __shfl_xor(a2, 4);
            a1 += __shfl_xor(a1, 8); a2 += __shfl_xor(a2, 8);
            if (lm == 0) {
                wsum1[wv * 64 + m * 16 + qd * 4 + r] = a1;
                wsum2[wv * 64 + m * 16 + qd * 4 + r] = a2;
            }
        }
    }
    __syncthreads();
    if (t < 64) {
        float s1 = wsum1[t] + wsum1[64 + t] + wsum1[128 + t] + wsum1[192 + t];
        float s2 = wsum2[t] + wsum2[64 + t] + wsum2[128 + t] + wsum2[192 + t];
        float mean = s1 * (1.f / 64.f);
        float var = s2 * (1.f / 64.f) - mean * mean;
        stat_m[t] = mean;
        stat_r[t] = rsqrtf(fmaxf(var, 0.f) + 1e-5f);
    }
    __syncthreads();

    #pragma unroll
    for (int m = 0; m < 4; ++m)
        #pragma unroll
        for (int r = 0; r < 4; ++r) {
            int row = m * 16 + qd * 4 + r;
            float v = (vreg[m][r] - stat_m[row]) * stat_r[row] * gn + btn;
            h1b[row * 72 + n] = bfbits(v);
        }
    __syncthreads();

    // ---- GEMM 2 ----
    f32x4 acc2[4];
    #pragma unroll
    for (int m = 0; m < 4; ++m) {
        f32x4 acc = {0.f, 0.f, 0.f, 0.f};
        #pragma unroll
        for (int kk = 0; kk < 2; ++kk) {
            bfrag8 a = *(const bfrag8*)&h1b[(m * 16 + lm) * 72 + kk * 32 + qd * 8];
            acc = __builtin_amdgcn_mfma_f32_16x16x32_bf16(a, w2f[kk], acc, 0, 0, 0);
        }
        acc2[m] = acc;
    }
    __syncthreads();
    #pragma unroll
    for (int m = 0; m < 4; ++m)
        #pragma unroll
        for (int r = 0; r < 4; ++r)
            msgf[(m * 16 + qd * 4 + r) * 68 + n] = acc2[m][r] + b2n;
    __syncthreads();

    // ---- run-aggregated aggr atomics ----
    {
        int j = t & 63, q = t >> 6;
        float acc = 0.f;
        #pragma unroll
        for (int e = q * 16; e < q * 16 + 16; ++e) {
            acc += msgf[e * 68 + j];
            bool flush = (e - q * 16 == 15) || (dsts[e + 1] != dsts[e]);
            if (flush) {
                atomicAdd(&aggr[(size_t)dsts[e] * 64 + j], acc);
                acc = 0.f;
            }
        }
    }

    // ---- GEMM 3 ----
    bfrag8 c1f[2];
    #pragma unroll
    for (int kk = 0; kk < 2; ++kk)
        c1f[kk] = *(const bfrag8*)&c1p[((size_t)(kk * 4 + wv) * 64 + L) * 8];
    #pragma unroll
    for (int m = 0; m < 4; ++m) {
        f32x4 acc = {0.f, 0.f, 0.f, 0.f};
        #pragma unroll
        for (int kk = 0; kk < 2; ++kk) {
            const float* mp = &msgf[(m * 16 + lm) * 68 + kk * 32 + qd * 8];
            f32x4 p0 = *(const f32x4*)mp;
            f32x4 p1 = *(const f32x4*)(mp + 4);
            unsigned short tb[8];
            #pragma unroll
            for (int j = 0; j < 4; ++j) {
                tb[j]     = (unsigned short)bfbits(p0[j]);
                tb[4 + j] = (unsigned short)bfbits(p1[j]);
            }
            bfrag8 a = *(bfrag8*)tb;
            acc = __builtin_amdgcn_mfma_f32_16x16x32_bf16(a, c1f[kk], acc, 0, 0, 0);
        }
        #pragma unroll
        for (int r = 0; r < 4; ++r) {
            float v = acc[r] + cb1n;
            v = v > 0.f ? v : 0.01f * v;
            v *= cw2n;
            v += __shfl_xor(v, 1);
            v += __shfl_xor(v, 2);
            v += __shfl_xor(v, 4);
            v += __shfl_xor(v, 8);
            if (lm == 0) coefp[wv * 64 + m * 16 + qd * 4 + r] = v;
        }
    }
    __syncthreads();
    if (t < 64)
        coef_all[t] = coefp[t] + coefp[64 + t] + coefp[128 + t] + coefp[192 + t] + cb2[0];
    __syncthreads();

    if (t < 12) {
        int q = t / 3, ax = t - q * 3;
        float acc = 0.f;
        for (int e = q * 16; e < q * 16 + 16; ++e) {
            acc += xr_s[e * 3 + ax] * coef_all[e];
            bool flush = (e - q * 16 == 15) || (dsts[e + 1] != dsts[e]);
            if (flush) {
                atomicAdd(&xacc[dsts[e] * 3 + ax], acc);
                acc = 0.f;
            }
        }
    }
}

// ============ attention body: Q-frags in registers, 3-buffer LDS (25088 B) ============
template <int MMODE>
__device__ __forceinline__ void attn_body(
    char* sbuf, int bid, int nb1,
    const float* __restrict__ h1, const float* __restrict__ qw1,
    const bf16* __restrict__ k1, const bf16* __restrict__ v1,
    const unsigned long long* __restrict__ mq1, const float* __restrict__ mf1, long mrs1, long mcs1,
    float* __restrict__ pO1, float* __restrict__ pM1, float* __restrict__ pL1,
    int nrows1, int ncols1, int nsplit1,
    const float* __restrict__ h2, const float* __restrict__ qw2,
    const bf16* __restrict__ k2, const bf16* __restrict__ v2,
    const unsigned long long* __restrict__ mq2, const float* __restrict__ mf2, long mrs2, long mcs2,
    float* __restrict__ pO2, float* __restrict__ pM2, float* __restrict__ pL2,
    int nrows2, int ncols2, int nsplit2)
{
    const float *h, *qw, *mf;
    const bf16 *kkp, *vvp;
    const unsigned long long* mq;
    long mrs, mcs;
    float *pO, *pM, *pL;
    int n_rows, n_cols, nsplit;
    if (bid < nb1) {
        h = h1; qw = qw1; kkp = k1; vvp = v1; mq = mq1; mf = mf1; mrs = mrs1; mcs = mcs1;
        pO = pO1; pM = pM1; pL = pL1; n_rows = nrows1; n_cols = ncols1; nsplit = nsplit1;
    } else {
        h = h2; qw = qw2; kkp = k2; vvp = v2; mq = mq2; mf = mf2; mrs = mrs2; mcs = mcs2;
        pO = pO2; pM = pM2; pL = pL2; n_rows = nrows2; n_cols = ncols2; nsplit = nsplit2;
        bid -= nb1;
    }

    unsigned short* sP = (unsigned short*)sbuf;
    unsigned short* sK = (unsigned short*)(sbuf + 8192);
    unsigned short* sV = (unsigned short*)(sbuf + 16384);
    uint2* mtq = (uint2*)(sbuf + 24576);
    unsigned char* mt = (unsigned char*)(sbuf + 24576);

    const int t  = threadIdx.x;
    const int wv = t >> 6;
    const int lm = t & 15;
    const int qd = (t & 63) >> 4;
    const int rb = bid / nsplit;
    const int sp = bid - rb * nsplit;
    const int r0 = rb * 64;
    const int cols_per = n_cols / nsplit;
    const int c_begin = sp * cols_per;

    const int cP = t >> 3, segP = (t & 7) * 8;

    // ---- prologue staging: h -> sP (rows), qw^T -> sK ----
    #pragma unroll
    for (int u = 0; u < 2; ++u) {
        int rr = cP + 32 * u;
        const float* hp = h + (size_t)(r0 + rr) * 64 + segP;
        unsigned short tmp[8];
        #pragma unroll
        for (int j = 0; j < 8; ++j) tmp[j] = bfbits(hp[j]);
        *(uint4*)&sP[swz(rr, segP)] = *(uint4*)tmp;
        const float* qp = qw + (size_t)rr * 64 + segP;
        #pragma unroll
        for (int j = 0; j < 8; ++j) sK[swz(segP + j, rr)] = bfbits(qp[j]);
    }

    // ---- prefetch tile 0 ----
    uint4 kreg[2], vreg[2];
    unsigned long long mregq = 0;
    kreg[0] = *(const uint4*)(kkp + (size_t)(c_begin + cP) * 64 + segP);
    kreg[1] = *(const uint4*)(kkp + (size_t)(c_begin + cP + 32) * 64 + segP);
    vreg[0] = *(const uint4*)(vvp + (size_t)(c_begin + cP) * 64 + segP);
    vreg[1] = *(const uint4*)(vvp + (size_t)(c_begin + cP + 32) * 64 + segP);
    if (MMODE == 0 && t < 64)
        mregq = mq[(size_t)(c_begin >> 6) * n_rows + r0 + t];
    __syncthreads();

    // ---- prologue: q = lrelu(h @ qw) into regs ----
    float qv[4][4];
    {
        bfrag8 a0 = *(const bfrag8*)&sP[swz(wv * 16 + lm, qd * 8)];
        bfrag8 a1 = *(const bfrag8*)&sP[swz(wv * 16 + lm, 32 + qd * 8)];
        #pragma unroll
        for (int ns = 0; ns < 4; ++ns) {
            f32x4 acc = {0.f, 0.f, 0.f, 0.f};
            bfrag8 b0 = *(const bfrag8*)&sK[swz(ns * 16 + lm, qd * 8)];
            bfrag8 b1 = *(const bfrag8*)&sK[swz(ns * 16 + lm, 32 + qd * 8)];
            acc = __builtin_amdgcn_mfma_f32_16x16x32_bf16(a0, b0, acc, 0, 0, 0);
            acc = __builtin_amdgcn_mfma_f32_16x16x32_bf16(a1, b1, acc, 0, 0, 0);
            #pragma unroll
            for (int r = 0; r < 4; ++r) {
                float v = acc[r];
                qv[ns][r] = v > 0.f ? v : 0.01f * v;
            }
        }
    }
    __syncthreads();

    // ---- transpose q through sP, pick up loop-invariant A-fragments ----
    #pragma unroll
    for (int ns = 0; ns < 4; ++ns)
        #pragma unroll
        for (int r = 0; r < 4; ++r)
            sP[swz(wv * 16 + qd * 4 + r, ns * 16 + lm)] = bfbits(qv[ns][r]);
    __syncthreads();
    bfrag8 aq0 = *(const bfrag8*)&sP[swz(wv * 16 + lm, qd * 8)];
    bfrag8 aq1 = *(const bfrag8*)&sP[swz(wv * 16 + lm, 32 + qd * 8)];

    float rm[4];
    #pragma unroll
    for (int r = 0; r < 4; ++r) rm[r] = -1e30f;
    f32x4 o[4];
    #pragma unroll
    for (int ds = 0; ds < 4; ++ds) o[ds] = (f32x4){0.f, 0.f, 0.f, 0.f};
    f32x4 osum = {0.f, 0.f, 0.f, 0.f};
    const short ONE = (short)0x3F80;
    const bfrag8 bones = {ONE, ONE, ONE, ONE, ONE, ONE, ONE, ONE};

    const int nt = cols_per / 64;
    for (int tile = 0; tile < nt; ++tile) {
        #pragma unroll
        for (int u = 0; u < 2; ++u) {
            int cc = cP + 32 * u;
            *(uint4*)&sK[swz(cc, segP)] = kreg[u];
            unsigned x0 = vreg[u].x, x1 = vreg[u].y, x2 = vreg[u].z, x3 = vreg[u].w;
            sV[swz(segP + 0, cc)] = (unsigned short)x0;
            sV[swz(segP + 1, cc)] = (unsigned short)(x0 >> 16);
            sV[swz(segP + 2, cc)] = (unsigned short)x1;
            sV[swz(segP + 3, cc)] = (unsigned short)(x1 >> 16);
            sV[swz(segP + 4, cc)] = (unsigned short)x2;
            sV[swz(segP + 5, cc)] = (unsigned short)(x2 >> 16);
            sV[swz(segP + 6, cc)] = (unsigned short)x3;
            sV[swz(segP + 7, cc)] = (unsigned short)(x3 >> 16);
        }
        if (MMODE == 0) {
            if (t < 64) mtq[t] = make_uint2((unsigned)mregq, (unsigned)(mregq >> 32));
        } else {
            int c0 = c_begin + tile * 64;
            #pragma unroll
            for (int u = 0; u < 16; ++u) {
                int i = t + 256 * u;
                int r = i >> 6, c = i & 63;
                mt[r * 80 + c] = (unsigned char)(
                    mf[(size_t)(r0 + r) * mrs + (size_t)(c0 + c) * mcs] != 0.f);
            }
        }
        __syncthreads();

        if (tile + 1 < nt) {
            int c0n = c_begin + (tile + 1) * 64;
            kreg[0] = *(const uint4*)(kkp + (size_t)(c0n + cP) * 64 + segP);
            kreg[1] = *(const uint4*)(kkp + (size_t)(c0n + cP + 32) * 64 + segP);
            vreg[0] = *(const uint4*)(vvp + (size_t)(c0n + cP) * 64 + segP);
            vreg[1] = *(const uint4*)(vvp + (size_t)(c0n + cP + 32) * 64 + segP);
            if (MMODE == 0 && t < 64)
                mregq = mq[(size_t)(c0n >> 6) * n_rows + r0 + t];
        }

        f32x4 s[4];
        #pragma unroll
        for (int ns = 0; ns < 4; ++ns) {
            f32x4 acc = {0.f, 0.f, 0.f, 0.f};
            bfrag8 b0 = *(const bfrag8*)&sK[swz(ns * 16 + lm, qd * 8)];
            bfrag8 b1 = *(const bfrag8*)&sK[swz(ns * 16 + lm, 32 + qd * 8)];
            acc = __builtin_amdgcn_mfma_f32_16x16x32_bf16(aq0, b0, acc, 0, 0, 0);
            acc = __builtin_amdgcn_mfma_f32_16x16x32_bf16(aq1, b1, acc, 0, 0, 0);
            s[ns] = acc;
        }

        float alpha[4];
        #pragma unroll
        for (int r = 0; r < 4; ++r) {
            int rloc = wv * 16 + qd * 4 + r;
            float v0, v1, v2, v3;
            if (MMODE == 0) {
                uint2 w = mtq[rloc];
                v0 = (w.x >> lm) & 1        ? s[0][r] : -1000.f;
                v1 = (w.x >> (16 + lm)) & 1 ? s[1][r] : -1000.f;
                v2 = (w.y >> lm) & 1        ? s[2][r] : -1000.f;
                v3 = (w.y >> (16 + lm)) & 1 ? s[3][r] : -1000.f;
            } else {
                v0 = mt[rloc * 80 +  0 + lm] ? s[0][r] : -1000.f;
                v1 = mt[rloc * 80 + 16 + lm] ? s[1][r] : -1000.f;
                v2 = mt[rloc * 80 + 32 + lm] ? s[2][r] : -1000.f;
                v3 = mt[rloc * 80 + 48 + lm] ? s[3][r] : -1000.f;
            }
            float mx = quad_max(fmaxf(fmaxf(v0, v1), fmaxf(v2, v3)));
            float mn = fmaxf(rm[r], mx);
            float al = __expf(rm[r] - mn);
            rm[r] = mn; alpha[r] = al;
            float p0 = __expf(v0 - mn), p1 = __expf(v1 - mn);
            float p2 = __expf(v2 - mn), p3 = __expf(v3 - mn);
            sP[swz(rloc,  0 + lm)] = bfbits(p0);
            sP[swz(rloc, 16 + lm)] = bfbits(p1);
            sP[swz(rloc, 32 + lm)] = bfbits(p2);
            sP[swz(rloc, 48 + lm)] = bfbits(p3);
            osum[r] *= al;
        }
        #pragma unroll
        for (int ds = 0; ds < 4; ++ds)
            #pragma unroll
            for (int r = 0; r < 4; ++r) o[ds][r] *= alpha[r];

        __builtin_amdgcn_wave_barrier();
        asm volatile("" ::: "memory");

        {
            bfrag8 a0 = *(const bfrag8*)&sP[swz(wv * 16 + lm, qd * 8)];
            bfrag8 a1 = *(const bfrag8*)&sP[swz(wv * 16 + lm, 32 + qd * 8)];
            #pragma unroll
            for (int ds = 0; ds < 4; ++ds) {
                bfrag8 b0 = *(const bfrag8*)&sV[swz(ds * 16 + lm, qd * 8)];
                bfrag8 b1 = *(const bfrag8*)&sV[swz(ds * 16 + lm, 32 + qd * 8)];
                o[ds] = __builtin_amdgcn_mfma_f32_16x16x32_bf16(a0, b0, o[ds], 0, 0, 0);
                o[ds] = __builtin_amdgcn_mfma_f32_16x16x32_bf16(a1, b1, o[ds], 0, 0, 0);
            }
            osum = __builtin_amdgcn_mfma_f32_16x16x32_bf16(a0, bones, osum, 0, 0, 0);
            osum = __builtin_amdgcn_mfma_f32_16x16x32_bf16(a1, bones, osum, 0, 0, 0);
        }
        __syncthreads();
    }

    #pragma unroll
    for (int ds = 0; ds < 4; ++ds)
        #pragma unroll
        for (int r = 0; r < 4; ++r) {
            int row = r0 + wv * 16 + qd * 4 + r;
            pO[((size_t)sp * n_rows + row) * 64 + ds * 16 + lm] = o[ds][r];
        }
    if (lm == 0) {
        #pragma unroll
        for (int r = 0; r < 4; ++r) {
            int row = r0 + wv * 16 + qd * 4 + r;
            pM[(size_t)sp * n_rows + row] = rm[r];
            pL[(size_t)sp * n_rows + row] = osum[r];
        }
    }
}

// ============ mega kernel: LJF ordering — ALL attn blocks first, then edges ============
__global__ __launch_bounds__(256, 4) void mega_kernel(
    int nb1,
    const float* h1, const float* qw1, const bf16* k1, const bf16* v1,
    const unsigned long long* mq1, float* pO1, float* pM1, float* pL1,
    int nrows1, int ncols1, int ns1,
    const float* h2, const float* qw2, const bf16* k2, const bf16* v2,
    const unsigned long long* mq2, float* pO2, float* pM2, float* pL2,
    int nrows2, int ncols2, int ns2,
    const int* ordR, const float* coordsR, const bf16* hR,
    const int* srcR, const int* dstR, const bf16* efR,
    const unsigned short* w1pR, const float* b1R, const float* gR, const float* btR,
    const unsigned short* w2pR, const float* b2R,
    const unsigned short* c1pR, const float* cb1R, const float* cw2R, const float* cb2R,
    float* aggrR, float* xaccR,
    const int* ordL, const float* coordsL, const bf16* hL,
    const int* srcL, const int* dstL, const bf16* efL,
    const unsigned short* w1pL, const float* b1L, const float* gL, const float* btL,
    const unsigned short* w2pL, const float* b2L,
    const unsigned short* c1pL, const float* cb1L, const float* cw2L, const float* cb2L,
    float* aggrL, float* xaccL)
{
    __shared__ __align__(16) char sbuf[31232];
    int bid = blockIdx.x;
    const int nbAtt = (N_LIG / 64) * ns1 + (N_REC / 64) * ns2;
    if (bid < nbAtt) {
        attn_body<0>(sbuf, bid, nb1,
            h1, qw1, k1, v1, mq1, (const float*)0, 0L, 0L, pO1, pM1, pL1, nrows1, ncols1, ns1,
            h2, qw2, k2, v2, mq2, (const float*)0, 0L, 0L, pO2, pM2, pL2, nrows2, ncols2, ns2);
    } else {
        int eid = bid - nbAtt;
        if (eid < E_REC / 64)
            edge_body<F_RECc, 6, bf16>(sbuf, eid, ordR, coordsR, hR, srcR, dstR, efR,
                w1pR, b1R, gR, btR, w2pR, b2R, c1pR, cb1R, cw2R, cb2R, aggrR, xaccR);
        else
            edge_body<F_LIGc, 5, bf16>(sbuf, eid - E_REC / 64, ordL, coordsL, hL, srcL, dstL, efL,
                w1pL, b1L, gL, btL, w2pL, b2L, c1pL, cb1L, cw2L, cb2L, aggrL, xaccL);
    }
}

// ---- standalone fallbacks (tier 1/2) ----
template <int F, int K1S>
__global__ __launch_bounds__(256, 4) void edge_mfma_f(
    const int* order, const float* coords, const float* h,
    const int* src, const int* dst, const float* efeat,
    const unsigned short* w1p, const float* b1, const float* g, const float* bt,
    const unsigned short* w2p, const float* b2,
    const unsigned short* c1p, const float* cb1, const float* cw2, const float* cb2,
    float* aggr, float* xacc)
{
    __shared__ __align__(16) char sbuf[64 * (K1S * 32 + 8) * 2 + 5632];
    edge_body<F, K1S, float>(sbuf, blockIdx.x, order, coords, h, src, dst, efeat,
        w1p, b1, g, bt, w2p, b2, c1p, cb1, cw2, cb2, aggr, xacc);
}

__global__ __launch_bounds__(256, 4) void attn_f32mask(
    int nb1,
    const float* h1, const float* qw1, const bf16* k1, const bf16* v1,
    const float* mf1, long mrs1, long mcs1,
    float* pO1, float* pM1, float* pL1, int nrows1, int ncols1, int ns1,
    const float* h2, const float* qw2, const bf16* k2, const bf16* v2,
    const float* mf2, long mrs2, long mcs2,
    float* pO2, float* pM2, float* pL2, int nrows2, int ncols2, int ns2)
{
    __shared__ __align__(16) char sbuf[29696];
    attn_body<1>(sbuf, blockIdx.x, nb1,
        h1, qw1, k1, v1, (const unsigned long long*)0, mf1, mrs1, mcs1,
        pO1, pM1, pL1, nrows1, ncols1, ns1,
        h2, qw2, k2, v2, (const unsigned long long*)0, mf2, mrs2, mcs2,
        pO2, pM2, pL2, nrows2, ncols2, ns2);
}

// ============ node kernel (dual-graph, packed weights, vectorized staging) ============
__global__ __launch_bounds__(256, 3) void node_mfma(
    int nbl, int nbn,
    const float* h1, const float* __restrict__ aggr1, const int* __restrict__ cnt1,
    const float* att1, const float* __restrict__ origh1,
    const unsigned short* __restrict__ w1pa, const float* __restrict__ b1a,
    const float* __restrict__ ga, const float* __restrict__ bta,
    const unsigned short* __restrict__ w2pa, const float* __restrict__ b2a, float* out1,
    const float* h2, const float* __restrict__ aggr2, const int* __restrict__ cnt2,
    const float* att2, const float* __restrict__ origh2,
    const unsigned short* __restrict__ w1pb, const float* __restrict__ b1b,
    const float* __restrict__ gb, const float* __restrict__ btb,
    const unsigned short* __restrict__ w2pb, const float* __restrict__ b2b, float* out2,
    const float* __restrict__ ocl, const float* __restrict__ ccl,
    const float* __restrict__ xaccl, float* __restrict__ outxl,
    const float* __restrict__ ocr, const float* __restrict__ ccr,
    const float* __restrict__ xaccr, float* __restrict__ outxr)
{
    if ((int)blockIdx.x >= nbn) {
        int i = (blockIdx.x - nbn) * 256 + threadIdx.x;
        if (i < N_LIG * 3) {
            int node = i / 3;
            float invc = 1.f / fmaxf((float)cnt1[node], 1.f);
            outxl[i] = 0.25f * ocl[i] + 0.75f * ccl[i] + xaccl[i] * invc;
        } else {
            i -= N_LIG * 3;
            if (i < N_REC * 3) {
                int node = i / 3;
                float invc = 1.f / fmaxf((float)cnt2[node], 1.f);
                outxr[i] = 0.25f * ocr[i] + 0.75f * ccr[i] + xaccr[i] * invc;
            }
        }
        return;
    }

    const float *h, *aggr, *att, *orig_h, *b1, *g, *bt, *b2;
    const unsigned short *w1p, *w2p;
    const int* cnt;
    float* h_out;
    int n0;
    if ((int)blockIdx.x < nbl) {
        h = h1; aggr = aggr1; cnt = cnt1; att = att1; orig_h = origh1;
        w1p = w1pa; b1 = b1a; g = ga; bt = bta; w2p = w2pa; b2 = b2a; h_out = out1;
        n0 = blockIdx.x * 64;
    } else {
        h = h2; aggr = aggr2; cnt = cnt2; att = att2; orig_h = origh2;
        w1p = w1pb; b1 = b1b; g = gb; bt = btb; w2p = w2pb; b2 = b2b; h_out = out2;
        n0 = (blockIdx.x - nbl) * 64;
    }

    constexpr int KP = 264;
    __shared__ __align__(16) char smem[64 * KP * 2];
    __shared__ __align__(16) unsigned short h1b[64 * 72];
    __shared__ float sums[256], sums2[256];
    __shared__ float stat_m[64], stat_r[64];
    __shared__ float invc_s[64];
    unsigned short* xb  = (unsigned short*)smem;
    float*          h1f = (float*)smem;

    const int t  = threadIdx.x;
    const int wv = t >> 6;
    const int L  = t & 63;
    const int lm = t & 15;
    const int qd = (t & 63) >> 4;
    const int n  = wv * 16 + lm;

    bfrag8 w1f[8], w2f[2];
    #pragma unroll
    for (int kk = 0; kk < 8; ++kk)
        w1f[kk] = *(const bfrag8*)&w1p[((size_t)(kk * 4 + wv) * 64 + L) * 8];
    #pragma unroll
    for (int kk = 0; kk < 2; ++kk)
        w2f[kk] = *(const bfrag8*)&w2p[((size_t)(kk * 4 + wv) * 64 + L) * 8];
    const float b1n = b1[n], b2n = b2[n];

    if (t < 64) invc_s[t] = 1.f / fmaxf((float)cnt[n0 + t], 1.f);
    __syncthreads();

    // vectorized staging: 64 nodes x 4 arrays x 8 chunks(8 floats) = 2048 chunks
    #pragma unroll
    for (int it = 0; it < 8; ++it) {
        int idx = t + 256 * it;
        int e   = idx >> 5;
        int c   = idx & 31;
        int arr = c >> 3, ch = (c & 7) * 8;
        const float* sp;
        if      (arr == 0) sp = h      + (size_t)(n0 + e) * 64 + ch;
        else if (arr == 1) sp = aggr   + (size_t)(n0 + e) * 64 + ch;
        else if (arr == 2) sp = att    + (size_t)(n0 + e) * 64 + ch;
        else               sp = orig_h + (size_t)(n0 + e) * 64 + ch;
        float4 a = *(const float4*)sp;
        float4 b = *(const float4*)(sp + 4);
        float s = (arr == 1) ? invc_s[e] : 1.f;
        unsigned short tmp[8] = {
            (unsigned short)bfbits(a.x * s), (unsigned short)bfbits(a.y * s),
            (unsigned short)bfbits(a.z * s), (unsigned short)bfbits(a.w * s),
            (unsigned short)bfbits(b.x * s), (unsigned short)bfbits(b.y * s),
            (unsigned short)bfbits(b.z * s), (unsigned short)bfbits(b.w * s)};
        *(uint4*)&xb[e * KP + arr * 64 + ch] = *(uint4*)tmp;
    }
    __syncthreads();

    f32x4 acc1[4];
    #pragma unroll
    for (int m = 0; m < 4; ++m) {
        f32x4 acc = {0.f, 0.f, 0.f, 0.f};
        #pragma unroll
        for (int kk = 0; kk < 8; ++kk) {
            bfrag8 a = *(const bfrag8*)&xb[(m * 16 + lm) * KP + kk * 32 + qd * 8];
            acc = __builtin_amdgcn_mfma_f32_16x16x32_bf16(a, w1f[kk], acc, 0, 0, 0);
        }
        acc1[m] = acc;
    }
    __syncthreads();
    #pragma unroll
    for (int m = 0; m < 4; ++m)
        #pragma unroll
        for (int r = 0; r < 4; ++r) {
            int mr = m * 16 + qd * 4 + r;
            float v = acc1[m][r] + b1n;
            v = v > 0.f ? v : 0.01f * v;
            h1f[mr * 68 + n] = v;
        }
    __syncthreads();

    {
        int e = t >> 2, seg = (t & 3) * 16;
        float s1 = 0.f, s2 = 0.f;
        #pragma unroll
        for (int j = 0; j < 16; ++j) {
            float v = h1f[e * 68 + seg + j];
            s1 += v; s2 += v * v;
        }
        sums[t] = s1; sums2[t] = s2;
    }
    __syncthreads();
    if (t < 64) {
        float s1 = sums[4 * t] + sums[4 * t + 1] + sums[4 * t + 2] + sums[4 * t + 3];
        float s2 = sums2[4 * t] + sums2[4 * t + 1] + sums2[4 * t + 2] + sums2[4 * t + 3];
        float mean = s1 * (1.f / 64.f);
        float var = s2 * (1.f / 64.f) - mean * mean;
        stat_m[t] = mean;
        stat_r[t] = rsqrtf(fmaxf(var, 0.f) + 1e-5f);
    }
    __syncthreads();
    for (int idx = t; idx < 4096; idx += 256) {
        int e = idx >> 6, j = idx & 63;
        float v = (h1f[e * 68 + j] - stat_m[e]) * stat_r[e] * g[j] + bt[j];
        h1b[e * 72 + j] = bfbits(v);
    }
    __syncthreads();

    #pragma unroll
    for (int m = 0; m < 4; ++m) {
        f32x4 acc = {0.f, 0.f, 0.f, 0.f};
        #pragma unroll
        for (int kk = 0; kk < 2; ++kk) {
            bfrag8 a = *(const bfrag8*)&h1b[(m * 16 + lm) * 72 + kk * 32 + qd * 8];
            acc = __builtin_amdgcn_mfma_f32_16x16x32_bf16(a, w2f[kk], acc, 0, 0, 0);
        }
        #pragma unroll
        for (int r = 0; r < 4; ++r) {
            int row = n0 + m * 16 + qd * 4 + r;
            float o = acc[r] + b2n;
            float hv = h[(size_t)row * 64 + n];
            h_out[(size_t)row * 64 + n] = 0.5f * o + 0.5f * hv;
        }
    }
}

// ---------------- merge split partials ----------------
__global__ __launch_bounds__(64) void attn_merge2(
    const float* __restrict__ pO1, const float* __restrict__ pM1, const float* __restrict__ pL1,
    float* __restrict__ out1, int ns1,
    const float* __restrict__ pO2, const float* __restrict__ pM2, const float* __restrict__ pL2,
    float* __restrict__ out2, int ns2)
{
    int r = blockIdx.x;
    const float *pO, *pM, *pL; float* out; int n_rows, nsplit;
    if (r < N_LIG) { pO = pO1; pM = pM1; pL = pL1; out = out1; n_rows = N_LIG; nsplit = ns1; }
    else { r -= N_LIG; pO = pO2; pM = pM2; pL = pL2; out = out2; n_rows = N_REC; nsplit = ns2; }
    int d = threadIdx.x;
    float mstar = -1e30f;
    for (int s = 0; s < nsplit; ++s) mstar = fmaxf(mstar, pM[(size_t)s * n_rows + r]);
    float L = 0.f, O = 0.f;
    for (int s = 0; s < nsplit; ++s) {
        float w = __expf(pM[(size_t)s * n_rows + r] - mstar);
        L += pL[(size_t)s * n_rows + r] * w;
        O += pO[((size_t)s * n_rows + r) * 64 + d] * w;
    }
    out[(size_t)r * 64 + d] = O / L;
}

// ---------------- per-row attention (tier-2 fallback) ----------------
__global__ __launch_bounds__(256) void attn_row_kernel(
    const float* __restrict__ h, const float* __restrict__ qw,
    const bf16* __restrict__ k, const bf16* __restrict__ v,
    const float* __restrict__ mask, long mrs, long mcs,
    float* __restrict__ out, int n_cols)
{
    int row = blockIdx.x;
    int tid = threadIdx.x;
    extern __shared__ float sc[];
    __shared__ float hrow[64];
    __shared__ float qrow[64];
    __shared__ float red[4];
    __shared__ float opart[4][64];

    if (tid < 64) hrow[tid] = h[(size_t)row * 64 + tid];
    __syncthreads();
    if (tid < 64) {
        float a = 0.f;
        #pragma unroll 8
        for (int i = 0; i < 64; ++i) a += hrow[i] * qw[i * 64 + tid];
        qrow[tid] = a > 0.f ? a : 0.01f * a;
    }
    __syncthreads();

    float lmax = -1e30f;
    for (int c = tid; c < n_cols; c += 256) {
        const bf16* kr = k + (size_t)c * 64;
        float s = 0.f;
        #pragma unroll 8
        for (int i = 0; i < 64; ++i) s += qrow[i] * ldkv(kr, i);
        float m = mask[(size_t)row * mrs + (size_t)c * mcs];
        s = m * s - 1000.f * (1.f - m);
        sc[c] = s;
        lmax = fmaxf(lmax, s);
    }
    #pragma unroll
    for (int o = 32; o > 0; o >>= 1) lmax = fmaxf(lmax, __shfl_xor(lmax, o, 64));
    int wid = tid >> 6;
    if ((tid & 63) == 0) red[wid] = lmax;
    __syncthreads();
    float bmax = fmaxf(fmaxf(red[0], red[1]), fmaxf(red[2], red[3]));
    __syncthreads();

    float lsum = 0.f;
    for (int c = tid; c < n_cols; c += 256) {
        float e = __expf(sc[c] - bmax);
        sc[c] = e;
        lsum += e;
    }
    lsum = wave_sum(lsum);
    if ((tid & 63) == 0) red[wid] = lsum;
    __syncthreads();
    float inv = 1.f / (red[0] + red[1] + red[2] + red[3]);

    int dd = tid & 63;
    float o = 0.f;
    for (int c = wid; c < n_cols; c += 4) o += sc[c] * ldkv(v, (size_t)c * 64 + dd);
    opart[wid][dd] = o;
    __syncthreads();
    if (wid == 0)
        out[(size_t)row * 64 + dd] =
            (opart[0][dd] + opart[1][dd] + opart[2][dd] + opart[3][dd]) * inv;
}

extern "C" void kernel_launch(void* const* d_in, const int* in_sizes, int n_in,
                              void* d_out, int out_size, void* d_ws, size_t ws_size,
                              hipStream_t stream)
{
    const float* coords_lig      = (const float*)d_in[0];
    const float* h_lig           = (const float*)d_in[1];
    const float* orig_h_lig      = (const float*)d_in[2];
    const float* orig_coords_lig = (const float*)d_in[3];
    const float* coords_rec      = (const float*)d_in[4];
    const float* h_rec           = (const float*)d_in[5];
    const float* orig_h_rec      = (const float*)d_in[6];
    const float* orig_coords_rec = (const float*)d_in[7];
    const int* lig_src   = (const int*)d_in[8];
    const int* lig_dst   = (const int*)d_in[9];
    const float* lig_efeat = (const float*)d_in[10];
    const int* rec_src   = (const int*)d_in[11];
    const int* rec_dst   = (const int*)d_in[12];
    const float* rec_efeat = (const float*)d_in[13];
    const float* mask      = (const float*)d_in[14];
    const float *lig_em_w1 = (const float*)d_in[15], *lig_em_b1 = (const float*)d_in[16];
    const float *lig_em_g  = (const float*)d_in[17], *lig_em_bt = (const float*)d_in[18];
    const float *lig_em_w2 = (const float*)d_in[19], *lig_em_b2 = (const float*)d_in[20];
    const float *rec_em_w1 = (const float*)d_in[21], *rec_em_b1 = (const float*)d_in[22];
    const float *rec_em_g  = (const float*)d_in[23], *rec_em_bt = (const float*)d_in[24];
    const float *rec_em_w2 = (const float*)d_in[25], *rec_em_b2 = (const float*)d_in[26];
    const float *lig_cm_w1 = (const float*)d_in[27], *lig_cm_b1 = (const float*)d_in[28];
    const float *lig_cm_w2 = (const float*)d_in[29], *lig_cm_b2 = (const float*)d_in[30];
    const float *rec_cm_w1 = (const float*)d_in[31], *rec_cm_b1 = (const float*)d_in[32];
    const float *rec_cm_w2 = (const float*)d_in[33], *rec_cm_b2 = (const float*)d_in[34];
    const float *q_lig_w = (const float*)d_in[35], *k_lig_w = (const float*)d_in[36];
    const float *v_lig_w = (const float*)d_in[37], *q_rec_w = (const float*)d_in[38];
    const float *k_rec_w = (const float*)d_in[39], *v_rec_w = (const float*)d_in[40];
    const float *lig_nm_w1 = (const float*)d_in[41], *lig_nm_b1 = (const float*)d_in[42];
    const float *lig_nm_g  = (const float*)d_in[43], *lig_nm_bt = (const float*)d_in[44];
    const float *lig_nm_w2 = (const float*)d_in[45], *lig_nm_b2 = (const float*)d_in[46];
    const float *rec_nm_w1 = (const float*)d_in[47], *rec_nm_b1 = (const float*)d_in[48];
    const float *rec_nm_g  = (const float*)d_in[49], *rec_nm_bt = (const float*)d_in[50];
    const float *rec_nm_w2 = (const float*)d_in[51], *rec_nm_b2 = (const float*)d_in[52];

    char* wsb = (char*)d_ws;
    float* aggr_l = (float*)(wsb + 16);
    float* aggr_r = aggr_l + (size_t)N_LIG * 64;
    float* xacc_l = aggr_r + (size_t)N_REC * 64;
    float* xacc_r = xacc_l + (size_t)N_LIG * 3;
    int* counts_l = (int*)(xacc_r + (size_t)N_REC * 3);
    int* counts_r = counts_l + N_LIG;
    int* cursor_l = counts_r + N_REC;
    int* cursor_r = cursor_l + N_LIG;
    int* order_l  = cursor_r + N_REC;
    int* order_r  = order_l + E_LIG;
    unsigned short* p_rec1  = (unsigned short*)(order_r + E_REC);
    unsigned short* p_lig1  = p_rec1 + 6 * 2048;
    unsigned short* p_rec2  = p_lig1 + 5 * 2048;
    unsigned short* p_lig2  = p_rec2 + 2 * 2048;
    unsigned short* pc_rec1 = p_lig2 + 2 * 2048;
    unsigned short* pc_lig1 = pc_rec1 + 2 * 2048;
    unsigned short* pn_rec1 = pc_lig1 + 2 * 2048;
    unsigned short* pn_lig1 = pn_rec1 + 8 * 2048;
    unsigned short* pn_rec2 = pn_lig1 + 8 * 2048;
    unsigned short* pn_lig2 = pn_rec2 + 2 * 2048;
    char* kv_base = (char*)(pn_lig2 + 2 * 2048);
    const size_t core_b = (size_t)(kv_base - wsb);
    const size_t kv_b = (size_t)(N_LIG + N_REC) * 64 * 2 * 2;

    const size_t mq1_n = (size_t)(N_REC / 64) * N_LIG;
    const size_t mq2_n = (size_t)(N_LIG / 64) * N_REC;
    const size_t mq_all_b = (mq1_n + mq2_n) * 8;
    const size_t mir_b = (size_t)(N_LIG + N_REC) * 64 * 2
                       + ((size_t)E_LIG * F_LIGc + (size_t)E_REC * F_RECc) * 2;

    const size_t part_b_hi = ((size_t)8 * N_LIG * 64 + (size_t)4 * N_REC * 64) * 4
                           + ((size_t)8 * N_LIG + (size_t)4 * N_REC) * 2 * 4;
    const size_t part_b_lo = ((size_t)4 * N_LIG * 64 + (size_t)2 * N_REC * 64) * 4
                           + ((size_t)4 * N_LIG + (size_t)2 * N_REC) * 2 * 4;

    int tier, ns1, ns2;
    size_t part_b;
    if (ws_size >= core_b + kv_b + part_b_hi + mq_all_b + mir_b) {
        tier = 0; ns1 = 8; ns2 = 4; part_b = part_b_hi;
    } else if (ws_size >= core_b + kv_b + part_b_lo) {
        tier = 1; ns1 = 4; ns2 = 2; part_b = part_b_lo;
    } else {
        tier = 2; ns1 = 4; ns2 = 2; part_b = part_b_lo;
    }

    bf16* kb_l = (bf16*)kv_base;
    bf16* vb_l = kb_l + (size_t)N_LIG * 64;
    bf16* kb_r = vb_l + (size_t)N_LIG * 64;
    bf16* vb_r = kb_r + (size_t)N_REC * 64;
    float* pO1 = (float*)(kv_base + kv_b);
    float* pO2 = pO1 + (size_t)ns1 * N_LIG * 64;
    float* pM1 = pO2 + (size_t)ns2 * N_REC * 64;
    float* pL1 = pM1 + (size_t)ns1 * N_LIG;
    float* pM2 = pL1 + (size_t)ns1 * N_LIG;
    float* pL2 = pM2 + (size_t)ns2 * N_REC;
    unsigned long long* mqb  = (unsigned long long*)(kv_base + kv_b + part_b);
    unsigned long long* mqbT = mqb + mq1_n;
    bf16* hb_l  = (bf16*)(mqbT + mq2_n);
    bf16* hb_r  = hb_l + (size_t)N_LIG * 64;
    bf16* efb_l = hb_r + (size_t)N_REC * 64;
    bf16* efb_r = efb_l + (size_t)E_LIG * F_LIGc;

    float* out = (float*)d_out;
    float* x_lig_o = out;
    float* h_lig_o = out + 12288;
    float* x_rec_o = out + 274432;
    float* h_rec_o = out + 299008;

    const int nb1 = (N_LIG / 64) * ns1;
    const int nb2 = (N_REC / 64) * ns2;

    if (tier == 0) {
        zero_kernel<<<(N_LIG + N_REC + 255) / 256, 256, 0, stream>>>(
            (float*)counts_l, N_LIG + N_REC);
        prep_kernel<<<NB_PREP, 256, 0, stream>>>(
            mask, mqb, mqbT,
            h_lig, hb_l, h_rec, hb_r, lig_efeat, efb_l, rec_efeat, efb_r,
            k_lig_w, v_lig_w, k_rec_w, v_rec_w, kb_l, vb_l, kb_r, vb_r,
            aggr_l,
            lig_dst, rec_dst, counts_l, counts_r,
            rec_em_w1, lig_em_w1, rec_em_w2, lig_em_w2, rec_cm_w1, lig_cm_w1,
            rec_nm_w1, lig_nm_w1, rec_nm_w2, lig_nm_w2,
            p_rec1, p_lig1, p_rec2, p_lig2, pc_rec1, pc_lig1,
            pn_rec1, pn_lig1, pn_rec2, pn_lig2);
        scan2_kernel<<<2, 256, 0, stream>>>(counts_l, cursor_l, counts_r, cursor_r);
        scatter2_kernel<<<(E_LIG + E_REC) / 256, 256, 0, stream>>>(
            lig_dst, rec_dst, cursor_l, cursor_r, order_l, order_r);

        // fused attn (1024, LJF first) + edge_rec (4096) + edge_lig (1024)
        mega_kernel<<<nb1 + nb2 + (E_LIG + E_REC) / 64, 256, 0, stream>>>(
            nb1,
            h_lig, q_lig_w, kb_r, vb_r, mqb, pO1, pM1, pL1, N_LIG, N_REC, ns1,
            h_rec, q_rec_w, kb_l, vb_l, mqbT, pO2, pM2, pL2, N_REC, N_LIG, ns2,
            order_r, coords_rec, hb_r, rec_src, rec_dst, efb_r,
            p_rec1, rec_em_b1, rec_em_g, rec_em_bt, p_rec2, rec_em_b2,
            pc_rec1, rec_cm_b1, rec_cm_w2, rec_cm_b2, aggr_r, xacc_r,
            order_l, coords_lig, hb_l, lig_src, lig_dst, efb_l,
            p_lig1, lig_em_b1, lig_em_g, lig_em_bt, p_lig2, lig_em_b2,
            pc_lig1, lig_cm_b1, lig_cm_w2, lig_cm_b2, aggr_l, xacc_l);

        // standalone merge (12288 parallel blocks — R10 showed inline merge in
        // node_mfma is ~2x slower than this despite saving a launch)
        attn_merge2<<<N_LIG + N_REC, 64, 0, stream>>>(
            pO1, pM1, pL1, h_lig_o, ns1, pO2, pM2, pL2, h_rec_o, ns2);
    } else {
        zero_kernel<<<(N_ZERO + 255) / 256, 256, 0, stream>>>(aggr_l, N_ZERO);
        pack_frags<<<NB_PACK, 256, 0, stream>>>(
            rec_em_w1, lig_em_w1, rec_em_w2, lig_em_w2, rec_cm_w1, lig_cm_w1,
            rec_nm_w1, lig_nm_w1, rec_nm_w2, lig_nm_w2,
            p_rec1, p_lig1, p_rec2, p_lig2, pc_rec1, pc_lig1,
            pn_rec1, pn_lig1, pn_rec2, pn_lig2);
        hist2_kernel<<<(E_LIG + E_REC) / 256, 256, 0, stream>>>(
            lig_dst, rec_dst, counts_l, counts_r);
        scan2_kernel<<<2, 256, 0, stream>>>(counts_l, cursor_l, counts_r, cursor_r);
        scatter2_kernel<<<(E_LIG + E_REC) / 256, 256, 0, stream>>>(
            lig_dst, rec_dst, cursor_l, cursor_r, order_l, order_r);
        kv_proj_kernel<<<(2 * (N_LIG + N_REC)) / 4, 256, 0, stream>>>(
            h_lig, h_rec, k_lig_w, v_lig_w, k_rec_w, v_rec_w,
            kb_l, vb_l, kb_r, vb_r);

        edge_mfma_f<F_LIGc, 5><<<E_LIG / 64, 256, 0, stream>>>(
            order_l, coords_lig, h_lig, lig_src, lig_dst, lig_efeat,
            p_lig1, lig_em_b1, lig_em_g, lig_em_bt, p_lig2, lig_em_b2,
            pc_lig1, lig_cm_b1, lig_cm_w2, lig_cm_b2, aggr_l, xacc_l);
        edge_mfma_f<F_RECc, 6><<<E_REC / 64, 256, 0, stream>>>(
            order_r, coords_rec, h_rec, rec_src, rec_dst, rec_efeat,
            p_rec1, rec_em_b1, rec_em_g, rec_em_bt, p_rec2, rec_em_b2,
            pc_rec1, rec_cm_b1, rec_cm_w2, rec_cm_b2, aggr_r, xacc_r);
        if (tier == 1) {
            attn_f32mask<<<nb1 + nb2, 256, 0, stream>>>(
                nb1,
                h_lig, q_lig_w, kb_r, vb_r, mask, (long)N_REC, 1L,
                pO1, pM1, pL1, N_LIG, N_REC, ns1,
                h_rec, q_rec_w, kb_l, vb_l, mask, 1L, (long)N_REC,
                pO2, pM2, pL2, N_REC, N_LIG, ns2);
            attn_merge2<<<N_LIG + N_REC, 64, 0, stream>>>(
                pO1, pM1, pL1, h_lig_o, ns1, pO2, pM2, pL2, h_rec_o, ns2);
        } else {
            attn_row_kernel<<<N_LIG, 256, N_REC * sizeof(float), stream>>>(
                h_lig, q_lig_w, kb_r, vb_r, mask, (long)N_REC, 1L, h_lig_o, N_REC);
            attn_row_kernel<<<N_REC, 256, N_LIG * sizeof(float), stream>>>(
                h_rec, q_rec_w, kb_l, vb_l, mask, 1L, (long)N_REC, h_rec_o, N_LIG);
        }
    }

    // node updates (192 blocks) + fused coordinate outputs (144 blocks)
    const int nbn = N_LIG / 64 + N_REC / 64;
    const int nbc = ((N_LIG + N_REC) * 3 + 255) / 256;
    node_mfma<<<nbn + nbc, 256, 0, stream>>>(
        N_LIG / 64, nbn,
        h_lig, aggr_l, counts_l, h_lig_o, orig_h_lig,
        pn_lig1, lig_nm_b1, lig_nm_g, lig_nm_bt, pn_lig2, lig_nm_b2, h_lig_o,
        h_rec, aggr_r, counts_r, h_rec_o, orig_h_rec,
        pn_rec1, rec_nm_b1, rec_nm_g, rec_nm_bt, pn_rec2, rec_nm_b2, h_rec_o,
        orig_coords_lig, coords_lig, xacc_l, x_lig_o,
        orig_coords_rec, coords_rec, xacc_r, x_rec_o);
}